// Round 5
// baseline (425.302 us; speedup 1.0000x reference)
//
#include <hip/hip_runtime.h>

#define DIN 128
#define DH 64
#define DOUT 32
#define BN_EPS 1e-5f

#define BK 512          // nodes per bucket (fat buckets: tail lines fill 4x faster -> less writeback amp)
#define BKSH 9          // log2(BK)
#define CAP 9216        // max edges per bucket in node-sorted col[] (mean ~8186, +11 sigma)
#define NSUB 32         // cursors per bucket: 8 XCD shards x 4 wave sub-cursors
#define SUBCAP 512      // slots per sub-list (mean ~256, +16 sigma)
#define SUBSH 9         // log2(SUBCAP)

// bf16 helpers (RNE store, exact load)
__device__ __forceinline__ unsigned short f2bf(float f) {
    union { float f; unsigned u; } v; v.f = f;
    unsigned r = (v.u + 0x7FFFu + ((v.u >> 16) & 1u)) >> 16;
    return (unsigned short)r;
}
__device__ __forceinline__ float bf2f(unsigned short h) {
    union { unsigned u; float f; } v; v.u = ((unsigned)h) << 16;
    return v.f;
}

// ---------------- bucket binning, XCD-sharded cursors ----------------
// recs[(b*NSUB + cursor)*SUBCAP + slot] = (src << 9) | dst_local

__global__ __launch_bounds__(256) void binscatter_k(const int* __restrict__ src, const int* __restrict__ dst,
                                                    int* __restrict__ cnt, unsigned* __restrict__ recs, int E) {
    int i = blockIdx.x * 256 + threadIdx.x;
    int cursor = ((blockIdx.x & 7) << 2) | ((threadIdx.x >> 6) & 3);
    if (i < E) {
        int s = src[i], d = dst[i];
        int b = d >> BKSH, dl = d & (BK - 1);
        int c = b * NSUB + cursor;
        int r = atomicAdd(&cnt[c], 1);
        if (r < SUBCAP) recs[((size_t)c << SUBSH) + r] = ((unsigned)s << BKSH) | (unsigned)dl;
    }
}

// ---------------- bucket (32 sub-lists) -> node-sorted CSR ----------------
// col[] gets src ids grouped by dst; rpde[g] = {start, deg}; dis[g] = rsqrt(deg+1)

__global__ __launch_bounds__(256) void csr_k(const unsigned* __restrict__ recs, const int* __restrict__ cnt,
                                             float* __restrict__ dis, int2* __restrict__ rpde,
                                             int* __restrict__ col, int n) {
    __shared__ int deg[BK], bas[BK], cur[BK];
    __shared__ int sa[BK], sb[BK];
    __shared__ int scnt[NSUB];
    int b = blockIdx.x, tid = threadIdx.x;
    for (int i = tid; i < BK; i += 256) { deg[i] = 0; cur[i] = 0; }
    if (tid < NSUB) scnt[tid] = min(cnt[b * NSUB + tid], SUBCAP);
    __syncthreads();
    const unsigned* rb = recs + ((size_t)b * NSUB << SUBSH);
    // histogram over all 32 sub-lists (flattened NSUB*SUBCAP slots)
    for (int s = tid; s < (NSUB << SUBSH); s += 256) {
        if ((s & (SUBCAP - 1)) < scnt[s >> SUBSH])
            atomicAdd(&deg[rb[s] & (BK - 1)], 1);
    }
    __syncthreads();
    for (int i = tid; i < BK; i += 256) sa[i] = deg[i];
    __syncthreads();
    // inclusive scan over BK, double-buffered Hillis-Steele
    int* pin = sa; int* pout = sb;
    for (int off = 1; off < BK; off <<= 1) {
        for (int i = tid; i < BK; i += 256) {
            int v = pin[i];
            if (i >= off) v += pin[i - off];
            pout[i] = v;
        }
        __syncthreads();
        int* t = pin; pin = pout; pout = t;
    }
    for (int i = tid; i < BK; i += 256) {
        bas[i] = pin[i] - deg[i];
        int g = b * BK + i;
        if (g < n) {
            dis[g] = rsqrtf((float)(deg[i] + 1));   // +1 self-loop
            rpde[g] = make_int2(b * CAP + bas[i], deg[i]);
        }
    }
    __syncthreads();
    for (int s = tid; s < (NSUB << SUBSH); s += 256) {
        if ((s & (SUBCAP - 1)) < scnt[s >> SUBSH]) {
            unsigned r = rb[s];
            int dl = r & (BK - 1);
            int k = atomicAdd(&cur[dl], 1);
            col[b * CAP + bas[dl] + k] = (int)(r >> BKSH);
        }
    }
}

// ---------------- GEMM1: h1s = bf16((x @ W1) * dis[row])  (N x 128 @ 128 x 64) ----------------

__global__ __launch_bounds__(256) void gemm1_k(const float* __restrict__ x, const float* __restrict__ W1,
                                               const float* __restrict__ dis, unsigned short* __restrict__ h1s,
                                               int n) {
    __shared__ __attribute__((aligned(16))) float xs[64][132];
    __shared__ __attribute__((aligned(16))) float ws[128][64];
    int r0b = blockIdx.x * 64;

    const float4* w4 = (const float4*)W1;
    float4* ws4 = (float4*)&ws[0][0];
    for (int i = threadIdx.x; i < 2048; i += 256) ws4[i] = w4[i];
    for (int i = threadIdx.x; i < 2048; i += 256) {
        int lin = i * 4;
        int r = lin >> 7, k = lin & 127;
        int gr = r0b + r;
        float4 v = make_float4(0.f, 0.f, 0.f, 0.f);
        if (gr < n) v = ((const float4*)x)[(gr * 128 + k) >> 2];
        *(float4*)&xs[r][k] = v;
    }
    __syncthreads();

    int tx = threadIdx.x & 15, ty = threadIdx.x >> 4;
    int c0 = tx * 4, r0 = ty * 4;
    float acc[4][4] = {};
    for (int k = 0; k < 128; k++) {
        float4 b = *(const float4*)&ws[k][c0];
        float a0 = xs[r0 + 0][k], a1 = xs[r0 + 1][k], a2 = xs[r0 + 2][k], a3 = xs[r0 + 3][k];
        acc[0][0] += a0 * b.x; acc[0][1] += a0 * b.y; acc[0][2] += a0 * b.z; acc[0][3] += a0 * b.w;
        acc[1][0] += a1 * b.x; acc[1][1] += a1 * b.y; acc[1][2] += a1 * b.z; acc[1][3] += a1 * b.w;
        acc[2][0] += a2 * b.x; acc[2][1] += a2 * b.y; acc[2][2] += a2 * b.z; acc[2][3] += a2 * b.w;
        acc[3][0] += a3 * b.x; acc[3][1] += a3 * b.y; acc[3][2] += a3 * b.z; acc[3][3] += a3 * b.w;
    }
    for (int i = 0; i < 4; i++) {
        int gr = r0b + r0 + i;
        if (gr < n) {
            float dd = dis[gr];
            ushort4 o;
            o.x = f2bf(acc[i][0] * dd);
            o.y = f2bf(acc[i][1] * dd);
            o.z = f2bf(acc[i][2] * dd);
            o.w = f2bf(acc[i][3] * dd);
            *(ushort4*)&h1s[gr * 64 + c0] = o;
        }
    }
}

// ---------------- Aggregation layer 1: wave per node, 64 lanes = 64 feats, bf16 gather-sum ----------------

__global__ __launch_bounds__(256) void agg1_k(const unsigned short* __restrict__ h1s,
                                              const int2* __restrict__ rpde,
                                              const int* __restrict__ col, float* __restrict__ out, int n) {
    int node = (blockIdx.x * 256 + threadIdx.x) >> 6;
    int f = threadIdx.x & 63;
    if (node >= n) return;
    int2 rd = rpde[node];
    int e = rd.x, ee = rd.x + rd.y;
    float a0 = 0.f, a1 = 0.f, a2 = 0.f, a3 = 0.f;
    for (; e + 3 < ee; e += 4) {
        int s0 = col[e], s1 = col[e + 1], s2 = col[e + 2], s3 = col[e + 3];
        a0 += bf2f(h1s[s0 * 64 + f]);
        a1 += bf2f(h1s[s1 * 64 + f]);
        a2 += bf2f(h1s[s2 * 64 + f]);
        a3 += bf2f(h1s[s3 * 64 + f]);
    }
    for (; e < ee; e++) a0 += bf2f(h1s[col[e] * 64 + f]);
    float dn = rsqrtf((float)(rd.y + 1));
    out[node * 64 + f] = (a0 + a1 + a2 + a3 + bf2f(h1s[node * 64 + f])) * dn;
}

// ---------------- BN stats ----------------

__global__ __launch_bounds__(256) void bnstats_k(const float* __restrict__ agg1, float* __restrict__ stats, int n) {
    int f = threadIdx.x & 63, g = threadIdx.x >> 6;
    float sum = 0.f, sq = 0.f;
    for (int r = blockIdx.x * 4 + g; r < n; r += gridDim.x * 4) {
        float v = agg1[r * 64 + f];
        sum += v; sq += v * v;
    }
    __shared__ float s1[4][64], s2[4][64];
    s1[g][f] = sum; s2[g][f] = sq;
    __syncthreads();
    if (g == 0) {
        sum = s1[0][f] + s1[1][f] + s1[2][f] + s1[3][f];
        sq  = s2[0][f] + s2[1][f] + s2[2][f] + s2[3][f];
        atomicAdd(&stats[f], sum);
        atomicAdd(&stats[64 + f], sq);
    }
}

// BN folded: h = relu(agg1 * s + t);  b1 cancels in centering (shift invariance).
__global__ __launch_bounds__(64) void bnfin_k(const float* __restrict__ stats, const float* __restrict__ gamma,
                                              const float* __restrict__ beta, float* __restrict__ st, float invn) {
    int f = threadIdx.x;
    if (f < 64) {
        float mean = stats[f] * invn;
        float var = stats[64 + f] * invn - mean * mean;
        float s = gamma[f] * rsqrtf(var + BN_EPS);
        st[f] = s;
        st[64 + f] = beta[f] - mean * s;
    }
}

// ---------------- GEMM2: h2s = bf16((relu(agg1*s+t) @ W2) * dis[row])  (N x 64 @ 64 x 32) ----------------

__global__ __launch_bounds__(256) void gemm2_k(const float* __restrict__ agg1, const float* __restrict__ W2,
                                               const float* __restrict__ st, const float* __restrict__ dis,
                                               unsigned short* __restrict__ h2s, int n) {
    __shared__ __attribute__((aligned(16))) float xs[64][68];
    __shared__ __attribute__((aligned(16))) float ws2[64][32];
    __shared__ float s_s[64], s_t[64];
    if (threadIdx.x < 64) {
        s_s[threadIdx.x] = st[threadIdx.x];
        s_t[threadIdx.x] = st[64 + threadIdx.x];
    }
    for (int i = threadIdx.x; i < 512; i += 256)
        ((float4*)&ws2[0][0])[i] = ((const float4*)W2)[i];
    __syncthreads();

    int r0b = blockIdx.x * 64;
    for (int i = threadIdx.x; i < 1024; i += 256) {
        int lin = i * 4;
        int r = lin >> 6, k = lin & 63;
        int gr = r0b + r;
        float4 v = make_float4(0.f, 0.f, 0.f, 0.f);
        if (gr < n) v = ((const float4*)agg1)[(gr * 64 + k) >> 2];
        v.x = fmaxf(v.x * s_s[k + 0] + s_t[k + 0], 0.f);
        v.y = fmaxf(v.y * s_s[k + 1] + s_t[k + 1], 0.f);
        v.z = fmaxf(v.z * s_s[k + 2] + s_t[k + 2], 0.f);
        v.w = fmaxf(v.w * s_s[k + 3] + s_t[k + 3], 0.f);
        *(float4*)&xs[r][k] = v;
    }
    __syncthreads();

    int c = threadIdx.x & 31, ty = threadIdx.x >> 5;
    float acc[8] = {};
    for (int k = 0; k < 64; k++) {
        float b = ws2[k][c];
        #pragma unroll
        for (int i = 0; i < 8; i++) acc[i] += xs[ty * 8 + i][k] * b;
    }
    for (int i = 0; i < 8; i++) {
        int gr = r0b + ty * 8 + i;
        if (gr < n) h2s[gr * 32 + c] = f2bf(acc[i] * dis[gr]);
    }
}

// ---------------- Aggregation layer 2: wave per node, 2 half-waves x 32 feats, bf16 gathers ----------------

__global__ __launch_bounds__(256) void agg2_k(const unsigned short* __restrict__ h2s,
                                              const int2* __restrict__ rpde,
                                              const int* __restrict__ col, const float* __restrict__ b2,
                                              float* __restrict__ out, int n) {
    int node = (blockIdx.x * 256 + threadIdx.x) >> 6;
    int lane = threadIdx.x & 63;
    if (node >= n) return;
    int f = lane & 31, half = lane >> 5;
    int2 rd = rpde[node];
    int e = rd.x + half, ee = rd.x + rd.y;
    float a0 = 0.f, a1 = 0.f;
    for (; e + 2 < ee; e += 4) {
        int s0 = col[e], s1 = col[e + 2];
        a0 += bf2f(h2s[s0 * 32 + f]);
        a1 += bf2f(h2s[s1 * 32 + f]);
    }
    for (; e < ee; e += 2) a0 += bf2f(h2s[col[e] * 32 + f]);
    float acc = a0 + a1;
    acc += __shfl_down(acc, 32, 64);
    if (half == 0) {
        float dn = rsqrtf((float)(rd.y + 1));
        out[node * 32 + f] = (acc + bf2f(h2s[node * 32 + f])) * dn + b2[f];
    }
}

// ---------------- launch ----------------

extern "C" void kernel_launch(void* const* d_in, const int* in_sizes, int n_in,
                              void* d_out, int out_size, void* d_ws, size_t ws_size,
                              hipStream_t stream) {
    const float* x      = (const float*)d_in[0];
    const int*   ei     = (const int*)d_in[1];
    const float* W1     = (const float*)d_in[2];
    // d_in[3] = b1 (cancels inside BN)
    const float* gamma1 = (const float*)d_in[4];
    const float* beta1  = (const float*)d_in[5];
    const float* W2     = (const float*)d_in[6];
    const float* b2     = (const float*)d_in[7];
    float* out = (float*)d_out;

    int N = in_sizes[0] / DIN;
    int E = in_sizes[1] / 2;
    const int* src = ei;
    const int* dst = ei + E;
    int NB = (N + BK - 1) / BK;   // buckets

    size_t off = 0;  // 4B units
    auto alloc = [&](size_t elems) -> void* {
        void* p = (char*)d_ws + off * 4;
        off += (elems + 127) & ~size_t(127);
        return p;
    };
    int*            cnt   = (int*)alloc((size_t)NB * NSUB);
    unsigned*       recs  = (unsigned*)alloc((size_t)NB * NSUB * SUBCAP);
    int*            col   = (int*)alloc((size_t)NB * CAP);
    float*          dis   = (float*)alloc(N);
    int2*           rpde  = (int2*)alloc((size_t)N * 2);
    float*          stats = (float*)alloc(128);
    float*          st    = (float*)alloc(128);
    unsigned short* h1s   = (unsigned short*)alloc((size_t)N * DH / 2);   // bf16
    float*          agg1  = (float*)alloc((size_t)N * DH);
    unsigned short* h2s   = h1s;  // h1s dead after agg1_k; N*32 bf16 <= N*64 bf16

    hipMemsetAsync(cnt, 0, (size_t)NB * NSUB * sizeof(int), stream);
    hipMemsetAsync(stats, 0, 128 * sizeof(float), stream);

    int gE = (E + 255) / 256;
    binscatter_k<<<gE, 256, 0, stream>>>(src, dst, cnt, recs, E);
    csr_k<<<NB, 256, 0, stream>>>(recs, cnt, dis, rpde, col, N);

    gemm1_k<<<(N + 63) / 64, 256, 0, stream>>>(x, W1, dis, h1s, N);
    agg1_k<<<(N + 3) / 4, 256, 0, stream>>>(h1s, rpde, col, agg1, N);

    bnstats_k<<<400, 256, 0, stream>>>(agg1, stats, N);
    bnfin_k<<<1, 64, 0, stream>>>(stats, gamma1, beta1, st, 1.0f / (float)N);

    gemm2_k<<<(N + 63) / 64, 256, 0, stream>>>(agg1, W2, st, dis, h2s, N);
    agg2_k<<<(N + 3) / 4, 256, 0, stream>>>(h2s, rpde, col, b2, out, N);
}

// Round 6
// 344.772 us; speedup vs baseline: 1.2336x; 1.2336x over previous
//
#include <hip/hip_runtime.h>

#define DIN 128
#define DH 64
#define DOUT 32
#define BN_EPS 1e-5f

#define BK 128          // nodes per bucket
#define BKSH 7          // log2(BK)
#define NBK_MAX 784     // ceil(100000/128)=782, padded
#define G 512           // counting-sort partition blocks (fixed; scan_k assumes 512)

// bf16 helpers (RNE store, exact load)
__device__ __forceinline__ unsigned short f2bf(float f) {
    union { float f; unsigned u; } v; v.f = f;
    unsigned r = (v.u + 0x7FFFu + ((v.u >> 16) & 1u)) >> 16;
    return (unsigned short)r;
}
__device__ __forceinline__ float bf2f(unsigned short h) {
    union { unsigned u; float f; } v; v.u = ((unsigned)h) << 16;
    return v.f;
}

// ---------------- counting sort pass 1: per-block bucket histogram ----------------

__global__ __launch_bounds__(256) void hist_k(const int* __restrict__ dst, int* __restrict__ hist_g,
                                              int E, int nbk, int chunk) {
    __shared__ int hist[NBK_MAX];
    int g = blockIdx.x, tid = threadIdx.x;
    for (int b = tid; b < nbk; b += 256) hist[b] = 0;
    __syncthreads();
    int i0 = g * chunk, iend = min(i0 + chunk, E);
    for (int i = i0 + tid; i < iend; i += 256)
        atomicAdd(&hist[dst[i] >> BKSH], 1);
    __syncthreads();
    for (int b = tid; b < nbk; b += 256)
        hist_g[(size_t)g * nbk + b] = hist[b];   // coalesced row write
}

// ---------------- pass 2a: per-bucket exclusive scan over the G block-counts ----------------

__global__ __launch_bounds__(256) void scan_k(const int* __restrict__ hist_g, int* __restrict__ rowoff,
                                              int* __restrict__ tot, int nbk) {
    __shared__ int sa[G], sb[G];
    int b = blockIdx.x, tid = threadIdx.x;
    int v0 = hist_g[(size_t)tid * nbk + b];
    int v1 = hist_g[(size_t)(tid + 256) * nbk + b];
    sa[tid] = v0; sa[tid + 256] = v1;
    __syncthreads();
    int* pin = sa; int* pout = sb;
    for (int off = 1; off < G; off <<= 1) {
        int a0 = pin[tid] + ((tid >= off) ? pin[tid - off] : 0);
        int a1 = pin[tid + 256] + ((tid + 256 >= off) ? pin[tid + 256 - off] : 0);
        pout[tid] = a0; pout[tid + 256] = a1;
        __syncthreads();
        int* t = pin; pin = pout; pout = t;
    }
    rowoff[(size_t)b * G + tid] = pin[tid] - v0;               // exclusive, coalesced write
    rowoff[(size_t)b * G + tid + 256] = pin[tid + 256] - v1;
    if (tid == 0) tot[b] = pin[G - 1];
}

// ---------------- pass 2b: scan bucket totals -> bucket base offsets ----------------

__global__ __launch_bounds__(1024) void base_k(const int* __restrict__ tot, int* __restrict__ base,
                                               int nbk, int E) {
    __shared__ int sa[1024], sb[1024];
    int tid = threadIdx.x;
    int v = (tid < nbk) ? tot[tid] : 0;
    sa[tid] = v;
    __syncthreads();
    int* pin = sa; int* pout = sb;
    for (int off = 1; off < 1024; off <<= 1) {
        int a = pin[tid] + ((tid >= off) ? pin[tid - off] : 0);
        pout[tid] = a;
        __syncthreads();
        int* t = pin; pin = pout; pout = t;
    }
    if (tid < nbk) base[tid] = pin[tid] - v;
    if (tid == 0) base[nbk] = E;
}

// ---------------- pass 3: scatter records into dense bucket regions (no global atomics) ----------------
// recs[slot] = (src << 7) | dst_local, slots owned per (bucket, block) -> coalesced-in-time writes

__global__ __launch_bounds__(256) void scatter_k(const int* __restrict__ src, const int* __restrict__ dst,
                                                 const int* __restrict__ base, const int* __restrict__ rowoff,
                                                 unsigned* __restrict__ recs, int E, int nbk, int chunk) {
    __shared__ int cur[NBK_MAX];
    int g = blockIdx.x, tid = threadIdx.x;
    for (int b = tid; b < nbk; b += 256)
        cur[b] = base[b] + rowoff[(size_t)b * G + g];
    __syncthreads();
    int i0 = g * chunk, iend = min(i0 + chunk, E);
    for (int i = i0 + tid; i < iend; i += 256) {
        int s = src[i], d = dst[i];
        int b = d >> BKSH;
        int slot = atomicAdd(&cur[b], 1);   // LDS atomic
        recs[slot] = ((unsigned)s << BKSH) | (unsigned)(d & (BK - 1));
    }
}

// ---------------- pass 4: within-bucket node sort -> CSR (col grouped by dst) ----------------
// rpde[g] = {start, deg}; dis[g] = rsqrt(deg+1)

__global__ __launch_bounds__(256) void csr_k(const unsigned* __restrict__ recs, const int* __restrict__ base,
                                             float* __restrict__ dis, int2* __restrict__ rpde,
                                             int* __restrict__ col, int n) {
    __shared__ int deg[BK], bas[BK], cur[BK], sc[BK];
    int b = blockIdx.x, tid = threadIdx.x;
    if (tid < BK) { deg[tid] = 0; cur[tid] = 0; }
    __syncthreads();
    int lo = base[b], hi = base[b + 1];
    for (int e = lo + tid; e < hi; e += 256)
        atomicAdd(&deg[recs[e] & (BK - 1)], 1);
    __syncthreads();
    if (tid < BK) sc[tid] = deg[tid];
    __syncthreads();
    for (int off = 1; off < BK; off <<= 1) {
        int t = (tid >= off && tid < BK) ? sc[tid - off] : 0;
        __syncthreads();
        if (tid < BK) sc[tid] += t;
        __syncthreads();
    }
    if (tid < BK) {
        bas[tid] = sc[tid] - deg[tid];
        int g = b * BK + tid;
        if (g < n) {
            dis[g] = rsqrtf((float)(deg[tid] + 1));   // +1 self-loop
            rpde[g] = make_int2(lo + bas[tid], deg[tid]);
        }
    }
    __syncthreads();
    for (int e = lo + tid; e < hi; e += 256) {
        unsigned r = recs[e];
        int dl = r & (BK - 1);
        int k = atomicAdd(&cur[dl], 1);
        col[lo + bas[dl] + k] = (int)(r >> BKSH);
    }
}

// ---------------- GEMM1: h1s = bf16((x @ W1) * dis[row])  (N x 128 @ 128 x 64) ----------------

__global__ __launch_bounds__(256) void gemm1_k(const float* __restrict__ x, const float* __restrict__ W1,
                                               const float* __restrict__ dis, unsigned short* __restrict__ h1s,
                                               int n) {
    __shared__ __attribute__((aligned(16))) float xs[64][132];
    __shared__ __attribute__((aligned(16))) float ws[128][64];
    int r0b = blockIdx.x * 64;

    const float4* w4 = (const float4*)W1;
    float4* ws4 = (float4*)&ws[0][0];
    for (int i = threadIdx.x; i < 2048; i += 256) ws4[i] = w4[i];
    for (int i = threadIdx.x; i < 2048; i += 256) {
        int lin = i * 4;
        int r = lin >> 7, k = lin & 127;
        int gr = r0b + r;
        float4 v = make_float4(0.f, 0.f, 0.f, 0.f);
        if (gr < n) v = ((const float4*)x)[(gr * 128 + k) >> 2];
        *(float4*)&xs[r][k] = v;
    }
    __syncthreads();

    int tx = threadIdx.x & 15, ty = threadIdx.x >> 4;
    int c0 = tx * 4, r0 = ty * 4;
    float acc[4][4] = {};
    for (int k = 0; k < 128; k++) {
        float4 b = *(const float4*)&ws[k][c0];
        float a0 = xs[r0 + 0][k], a1 = xs[r0 + 1][k], a2 = xs[r0 + 2][k], a3 = xs[r0 + 3][k];
        acc[0][0] += a0 * b.x; acc[0][1] += a0 * b.y; acc[0][2] += a0 * b.z; acc[0][3] += a0 * b.w;
        acc[1][0] += a1 * b.x; acc[1][1] += a1 * b.y; acc[1][2] += a1 * b.z; acc[1][3] += a1 * b.w;
        acc[2][0] += a2 * b.x; acc[2][1] += a2 * b.y; acc[2][2] += a2 * b.z; acc[2][3] += a2 * b.w;
        acc[3][0] += a3 * b.x; acc[3][1] += a3 * b.y; acc[3][2] += a3 * b.z; acc[3][3] += a3 * b.w;
    }
    for (int i = 0; i < 4; i++) {
        int gr = r0b + r0 + i;
        if (gr < n) {
            float dd = dis[gr];
            ushort4 o;
            o.x = f2bf(acc[i][0] * dd);
            o.y = f2bf(acc[i][1] * dd);
            o.z = f2bf(acc[i][2] * dd);
            o.w = f2bf(acc[i][3] * dd);
            *(ushort4*)&h1s[gr * 64 + c0] = o;
        }
    }
}

// ---------------- Aggregation layer 1: wave per node, 64 lanes = 64 feats, bf16 gather-sum ----------------

__global__ __launch_bounds__(256) void agg1_k(const unsigned short* __restrict__ h1s,
                                              const int2* __restrict__ rpde,
                                              const int* __restrict__ col, float* __restrict__ out, int n) {
    int node = (blockIdx.x * 256 + threadIdx.x) >> 6;
    int f = threadIdx.x & 63;
    if (node >= n) return;
    int2 rd = rpde[node];
    int e = rd.x, ee = rd.x + rd.y;
    float a0 = 0.f, a1 = 0.f, a2 = 0.f, a3 = 0.f;
    for (; e + 3 < ee; e += 4) {
        int s0 = col[e], s1 = col[e + 1], s2 = col[e + 2], s3 = col[e + 3];
        a0 += bf2f(h1s[s0 * 64 + f]);
        a1 += bf2f(h1s[s1 * 64 + f]);
        a2 += bf2f(h1s[s2 * 64 + f]);
        a3 += bf2f(h1s[s3 * 64 + f]);
    }
    for (; e < ee; e++) a0 += bf2f(h1s[col[e] * 64 + f]);
    float dn = rsqrtf((float)(rd.y + 1));
    out[node * 64 + f] = (a0 + a1 + a2 + a3 + bf2f(h1s[node * 64 + f])) * dn;
}

// ---------------- BN stats ----------------

__global__ __launch_bounds__(256) void bnstats_k(const float* __restrict__ agg1, float* __restrict__ stats, int n) {
    int f = threadIdx.x & 63, g = threadIdx.x >> 6;
    float sum = 0.f, sq = 0.f;
    for (int r = blockIdx.x * 4 + g; r < n; r += gridDim.x * 4) {
        float v = agg1[r * 64 + f];
        sum += v; sq += v * v;
    }
    __shared__ float s1[4][64], s2[4][64];
    s1[g][f] = sum; s2[g][f] = sq;
    __syncthreads();
    if (g == 0) {
        sum = s1[0][f] + s1[1][f] + s1[2][f] + s1[3][f];
        sq  = s2[0][f] + s2[1][f] + s2[2][f] + s2[3][f];
        atomicAdd(&stats[f], sum);
        atomicAdd(&stats[64 + f], sq);
    }
}

// BN folded: h = relu(agg1 * s + t);  b1 cancels in centering (shift invariance).
__global__ __launch_bounds__(64) void bnfin_k(const float* __restrict__ stats, const float* __restrict__ gamma,
                                              const float* __restrict__ beta, float* __restrict__ st, float invn) {
    int f = threadIdx.x;
    if (f < 64) {
        float mean = stats[f] * invn;
        float var = stats[64 + f] * invn - mean * mean;
        float s = gamma[f] * rsqrtf(var + BN_EPS);
        st[f] = s;
        st[64 + f] = beta[f] - mean * s;
    }
}

// ---------------- GEMM2: h2s = bf16((relu(agg1*s+t) @ W2) * dis[row])  (N x 64 @ 64 x 32) ----------------

__global__ __launch_bounds__(256) void gemm2_k(const float* __restrict__ agg1, const float* __restrict__ W2,
                                               const float* __restrict__ st, const float* __restrict__ dis,
                                               unsigned short* __restrict__ h2s, int n) {
    __shared__ __attribute__((aligned(16))) float xs[64][68];
    __shared__ __attribute__((aligned(16))) float ws2[64][32];
    __shared__ float s_s[64], s_t[64];
    if (threadIdx.x < 64) {
        s_s[threadIdx.x] = st[threadIdx.x];
        s_t[threadIdx.x] = st[64 + threadIdx.x];
    }
    for (int i = threadIdx.x; i < 512; i += 256)
        ((float4*)&ws2[0][0])[i] = ((const float4*)W2)[i];
    __syncthreads();

    int r0b = blockIdx.x * 64;
    for (int i = threadIdx.x; i < 1024; i += 256) {
        int lin = i * 4;
        int r = lin >> 6, k = lin & 63;
        int gr = r0b + r;
        float4 v = make_float4(0.f, 0.f, 0.f, 0.f);
        if (gr < n) v = ((const float4*)agg1)[(gr * 64 + k) >> 2];
        v.x = fmaxf(v.x * s_s[k + 0] + s_t[k + 0], 0.f);
        v.y = fmaxf(v.y * s_s[k + 1] + s_t[k + 1], 0.f);
        v.z = fmaxf(v.z * s_s[k + 2] + s_t[k + 2], 0.f);
        v.w = fmaxf(v.w * s_s[k + 3] + s_t[k + 3], 0.f);
        *(float4*)&xs[r][k] = v;
    }
    __syncthreads();

    int c = threadIdx.x & 31, ty = threadIdx.x >> 5;
    float acc[8] = {};
    for (int k = 0; k < 64; k++) {
        float b = ws2[k][c];
        #pragma unroll
        for (int i = 0; i < 8; i++) acc[i] += xs[ty * 8 + i][k] * b;
    }
    for (int i = 0; i < 8; i++) {
        int gr = r0b + ty * 8 + i;
        if (gr < n) h2s[gr * 32 + c] = f2bf(acc[i] * dis[gr]);
    }
}

// ---------------- Aggregation layer 2: wave per node, 2 half-waves x 32 feats, bf16 gathers ----------------

__global__ __launch_bounds__(256) void agg2_k(const unsigned short* __restrict__ h2s,
                                              const int2* __restrict__ rpde,
                                              const int* __restrict__ col, const float* __restrict__ b2,
                                              float* __restrict__ out, int n) {
    int node = (blockIdx.x * 256 + threadIdx.x) >> 6;
    int lane = threadIdx.x & 63;
    if (node >= n) return;
    int f = lane & 31, half = lane >> 5;
    int2 rd = rpde[node];
    int e = rd.x + half, ee = rd.x + rd.y;
    float a0 = 0.f, a1 = 0.f;
    for (; e + 2 < ee; e += 4) {
        int s0 = col[e], s1 = col[e + 2];
        a0 += bf2f(h2s[s0 * 32 + f]);
        a1 += bf2f(h2s[s1 * 32 + f]);
    }
    for (; e < ee; e += 2) a0 += bf2f(h2s[col[e] * 32 + f]);
    float acc = a0 + a1;
    acc += __shfl_down(acc, 32, 64);
    if (half == 0) {
        float dn = rsqrtf((float)(rd.y + 1));
        out[node * 32 + f] = (acc + bf2f(h2s[node * 32 + f])) * dn + b2[f];
    }
}

// ---------------- launch ----------------

extern "C" void kernel_launch(void* const* d_in, const int* in_sizes, int n_in,
                              void* d_out, int out_size, void* d_ws, size_t ws_size,
                              hipStream_t stream) {
    const float* x      = (const float*)d_in[0];
    const int*   ei     = (const int*)d_in[1];
    const float* W1     = (const float*)d_in[2];
    // d_in[3] = b1 (cancels inside BN)
    const float* gamma1 = (const float*)d_in[4];
    const float* beta1  = (const float*)d_in[5];
    const float* W2     = (const float*)d_in[6];
    const float* b2     = (const float*)d_in[7];
    float* out = (float*)d_out;

    int N = in_sizes[0] / DIN;
    int E = in_sizes[1] / 2;
    const int* src = ei;
    const int* dst = ei + E;
    int nbk = (N + BK - 1) >> BKSH;         // 782
    int chunk = (E + G - 1) / G;

    size_t off = 0;  // 4B units
    auto alloc = [&](size_t elems) -> void* {
        void* p = (char*)d_ws + off * 4;
        off += (elems + 127) & ~size_t(127);
        return p;
    };
    int*            hist_g = (int*)alloc((size_t)G * NBK_MAX);
    int*            rowoff = (int*)alloc((size_t)NBK_MAX * G);
    int*            tot    = (int*)alloc(NBK_MAX);
    int*            base   = (int*)alloc(NBK_MAX + 1);
    unsigned*       recs   = (unsigned*)alloc((size_t)E);
    int*            col    = (int*)alloc((size_t)E);
    float*          dis    = (float*)alloc(N);
    int2*           rpde   = (int2*)alloc((size_t)N * 2);
    float*          stats  = (float*)alloc(128);
    float*          st     = (float*)alloc(128);
    unsigned short* h1s    = (unsigned short*)alloc((size_t)N * DH / 2);   // bf16
    float*          agg1   = (float*)alloc((size_t)N * DH);
    unsigned short* h2s    = h1s;  // h1s dead after agg1_k

    hipMemsetAsync(stats, 0, 128 * sizeof(float), stream);

    hist_k<<<G, 256, 0, stream>>>(dst, hist_g, E, nbk, chunk);
    scan_k<<<nbk, 256, 0, stream>>>(hist_g, rowoff, tot, nbk);
    base_k<<<1, 1024, 0, stream>>>(tot, base, nbk, E);
    scatter_k<<<G, 256, 0, stream>>>(src, dst, base, rowoff, recs, E, nbk, chunk);
    csr_k<<<nbk, 256, 0, stream>>>(recs, base, dis, rpde, col, N);

    gemm1_k<<<(N + 63) / 64, 256, 0, stream>>>(x, W1, dis, h1s, N);
    agg1_k<<<(N + 3) / 4, 256, 0, stream>>>(h1s, rpde, col, agg1, N);

    bnstats_k<<<400, 256, 0, stream>>>(agg1, stats, N);
    bnfin_k<<<1, 64, 0, stream>>>(stats, gamma1, beta1, st, 1.0f / (float)N);

    gemm2_k<<<(N + 63) / 64, 256, 0, stream>>>(agg1, W2, st, dis, h2s, N);
    agg2_k<<<(N + 3) / 4, 256, 0, stream>>>(h2s, rpde, col, b2, out, N);
}

// Round 7
// 316.181 us; speedup vs baseline: 1.3451x; 1.0904x over previous
//
#include <hip/hip_runtime.h>

#define DIN 128
#define DH 64
#define DOUT 32
#define BN_EPS 1e-5f

#define BK 128          // nodes per bucket
#define BKSH 7          // log2(BK)
#define NBK_MAX 784     // ceil(100000/128)=782, padded
#define G 512           // counting-sort partition blocks (fixed; scan_k assumes 512)

// bf16 helpers (RNE store, exact load)
__device__ __forceinline__ unsigned short f2bf(float f) {
    union { float f; unsigned u; } v; v.f = f;
    unsigned r = (v.u + 0x7FFFu + ((v.u >> 16) & 1u)) >> 16;
    return (unsigned short)r;
}
__device__ __forceinline__ float bf2f(unsigned short h) {
    union { unsigned u; float f; } v; v.u = ((unsigned)h) << 16;
    return v.f;
}

// ---------------- counting sort pass 1: per-block bucket histogram ----------------

__global__ __launch_bounds__(256) void hist_k(const int* __restrict__ dst, int* __restrict__ hist_g,
                                              int E, int nbk, int chunk) {
    __shared__ int hist[NBK_MAX];
    int g = blockIdx.x, tid = threadIdx.x;
    for (int b = tid; b < nbk; b += 256) hist[b] = 0;
    __syncthreads();
    int i0 = g * chunk, iend = min(i0 + chunk, E);
    for (int i = i0 + tid; i < iend; i += 256)
        atomicAdd(&hist[dst[i] >> BKSH], 1);
    __syncthreads();
    for (int b = tid; b < nbk; b += 256)
        hist_g[(size_t)g * nbk + b] = hist[b];   // coalesced row write
}

// ---------------- pass 2a: per-bucket exclusive scan over the G block-counts ----------------

__global__ __launch_bounds__(256) void scan_k(const int* __restrict__ hist_g, int* __restrict__ rowoff,
                                              int* __restrict__ tot, int nbk) {
    __shared__ int sa[G], sb[G];
    int b = blockIdx.x, tid = threadIdx.x;
    int v0 = hist_g[(size_t)tid * nbk + b];
    int v1 = hist_g[(size_t)(tid + 256) * nbk + b];
    sa[tid] = v0; sa[tid + 256] = v1;
    __syncthreads();
    int* pin = sa; int* pout = sb;
    for (int off = 1; off < G; off <<= 1) {
        int a0 = pin[tid] + ((tid >= off) ? pin[tid - off] : 0);
        int a1 = pin[tid + 256] + ((tid + 256 >= off) ? pin[tid + 256 - off] : 0);
        pout[tid] = a0; pout[tid + 256] = a1;
        __syncthreads();
        int* t = pin; pin = pout; pout = t;
    }
    rowoff[(size_t)b * G + tid] = pin[tid] - v0;               // exclusive, coalesced write
    rowoff[(size_t)b * G + tid + 256] = pin[tid + 256] - v1;
    if (tid == 0) tot[b] = pin[G - 1];
}

// ---------------- pass 2b: scan bucket totals -> bucket base offsets ----------------

__global__ __launch_bounds__(1024) void base_k(const int* __restrict__ tot, int* __restrict__ base,
                                               int nbk, int E) {
    __shared__ int sa[1024], sb[1024];
    int tid = threadIdx.x;
    int v = (tid < nbk) ? tot[tid] : 0;
    sa[tid] = v;
    __syncthreads();
    int* pin = sa; int* pout = sb;
    for (int off = 1; off < 1024; off <<= 1) {
        int a = pin[tid] + ((tid >= off) ? pin[tid - off] : 0);
        pout[tid] = a;
        __syncthreads();
        int* t = pin; pin = pout; pout = t;
    }
    if (tid < nbk) base[tid] = pin[tid] - v;
    if (tid == 0) base[nbk] = E;
}

// ---------------- pass 3: scatter records into dense bucket regions (no global atomics) ----------------

__global__ __launch_bounds__(256) void scatter_k(const int* __restrict__ src, const int* __restrict__ dst,
                                                 const int* __restrict__ base, const int* __restrict__ rowoff,
                                                 unsigned* __restrict__ recs, int E, int nbk, int chunk) {
    __shared__ int cur[NBK_MAX];
    int g = blockIdx.x, tid = threadIdx.x;
    for (int b = tid; b < nbk; b += 256)
        cur[b] = base[b] + rowoff[(size_t)b * G + g];
    __syncthreads();
    int i0 = g * chunk, iend = min(i0 + chunk, E);
    for (int i = i0 + tid; i < iend; i += 256) {
        int s = src[i], d = dst[i];
        int b = d >> BKSH;
        int slot = atomicAdd(&cur[b], 1);   // LDS atomic
        recs[slot] = ((unsigned)s << BKSH) | (unsigned)(d & (BK - 1));
    }
}

// ---------------- pass 4: within-bucket node sort -> CSR (col grouped by dst) ----------------

__global__ __launch_bounds__(256) void csr_k(const unsigned* __restrict__ recs, const int* __restrict__ base,
                                             float* __restrict__ dis, int2* __restrict__ rpde,
                                             int* __restrict__ col, int n) {
    __shared__ int deg[BK], bas[BK], cur[BK], sc[BK];
    int b = blockIdx.x, tid = threadIdx.x;
    if (tid < BK) { deg[tid] = 0; cur[tid] = 0; }
    __syncthreads();
    int lo = base[b], hi = base[b + 1];
    for (int e = lo + tid; e < hi; e += 256)
        atomicAdd(&deg[recs[e] & (BK - 1)], 1);
    __syncthreads();
    if (tid < BK) sc[tid] = deg[tid];
    __syncthreads();
    for (int off = 1; off < BK; off <<= 1) {
        int t = (tid >= off && tid < BK) ? sc[tid - off] : 0;
        __syncthreads();
        if (tid < BK) sc[tid] += t;
        __syncthreads();
    }
    if (tid < BK) {
        bas[tid] = sc[tid] - deg[tid];
        int g = b * BK + tid;
        if (g < n) {
            dis[g] = rsqrtf((float)(deg[tid] + 1));   // +1 self-loop
            rpde[g] = make_int2(lo + bas[tid], deg[tid]);
        }
    }
    __syncthreads();
    for (int e = lo + tid; e < hi; e += 256) {
        unsigned r = recs[e];
        int dl = r & (BK - 1);
        int k = atomicAdd(&cur[dl], 1);
        col[lo + bas[dl] + k] = (int)(r >> BKSH);
    }
}

// ---------------- GEMM1: h1s = bf16((x @ W1) * dis[row])  (N x 128 @ 128 x 64) ----------------

__global__ __launch_bounds__(256) void gemm1_k(const float* __restrict__ x, const float* __restrict__ W1,
                                               const float* __restrict__ dis, unsigned short* __restrict__ h1s,
                                               int n) {
    __shared__ __attribute__((aligned(16))) float xs[64][132];
    __shared__ __attribute__((aligned(16))) float ws[128][64];
    int r0b = blockIdx.x * 64;

    const float4* w4 = (const float4*)W1;
    float4* ws4 = (float4*)&ws[0][0];
    for (int i = threadIdx.x; i < 2048; i += 256) ws4[i] = w4[i];
    for (int i = threadIdx.x; i < 2048; i += 256) {
        int lin = i * 4;
        int r = lin >> 7, k = lin & 127;
        int gr = r0b + r;
        float4 v = make_float4(0.f, 0.f, 0.f, 0.f);
        if (gr < n) v = ((const float4*)x)[(gr * 128 + k) >> 2];
        *(float4*)&xs[r][k] = v;
    }
    __syncthreads();

    int tx = threadIdx.x & 15, ty = threadIdx.x >> 4;
    int c0 = tx * 4, r0 = ty * 4;
    float acc[4][4] = {};
    for (int k = 0; k < 128; k++) {
        float4 b = *(const float4*)&ws[k][c0];
        float a0 = xs[r0 + 0][k], a1 = xs[r0 + 1][k], a2 = xs[r0 + 2][k], a3 = xs[r0 + 3][k];
        acc[0][0] += a0 * b.x; acc[0][1] += a0 * b.y; acc[0][2] += a0 * b.z; acc[0][3] += a0 * b.w;
        acc[1][0] += a1 * b.x; acc[1][1] += a1 * b.y; acc[1][2] += a1 * b.z; acc[1][3] += a1 * b.w;
        acc[2][0] += a2 * b.x; acc[2][1] += a2 * b.y; acc[2][2] += a2 * b.z; acc[2][3] += a2 * b.w;
        acc[3][0] += a3 * b.x; acc[3][1] += a3 * b.y; acc[3][2] += a3 * b.z; acc[3][3] += a3 * b.w;
    }
    for (int i = 0; i < 4; i++) {
        int gr = r0b + r0 + i;
        if (gr < n) {
            float dd = dis[gr];
            ushort4 o;
            o.x = f2bf(acc[i][0] * dd);
            o.y = f2bf(acc[i][1] * dd);
            o.z = f2bf(acc[i][2] * dd);
            o.w = f2bf(acc[i][3] * dd);
            *(ushort4*)&h1s[gr * 64 + c0] = o;
        }
    }
}

// ---------------- Aggregation layer 1: wave per node, 64 lanes = 64 feats, 8 gathers in flight ----------------

__global__ __launch_bounds__(256) void agg1_k(const unsigned short* __restrict__ h1s,
                                              const int2* __restrict__ rpde,
                                              const int* __restrict__ col, float* __restrict__ out, int n) {
    int node = (blockIdx.x * 256 + threadIdx.x) >> 6;
    int f = threadIdx.x & 63;
    if (node >= n) return;
    int2 rd = rpde[node];
    int e  = __builtin_amdgcn_readfirstlane(rd.x);   // wave-uniform row start -> scalar col loads
    int dg = __builtin_amdgcn_readfirstlane(rd.y);
    int ee = e + dg;
    float a0 = 0.f, a1 = 0.f, a2 = 0.f, a3 = 0.f, a4 = 0.f, a5 = 0.f, a6 = 0.f, a7 = 0.f;
    for (; e + 7 < ee; e += 8) {
        int s0 = col[e],     s1 = col[e + 1], s2 = col[e + 2], s3 = col[e + 3];
        int s4 = col[e + 4], s5 = col[e + 5], s6 = col[e + 6], s7 = col[e + 7];
        a0 += bf2f(h1s[s0 * 64 + f]);
        a1 += bf2f(h1s[s1 * 64 + f]);
        a2 += bf2f(h1s[s2 * 64 + f]);
        a3 += bf2f(h1s[s3 * 64 + f]);
        a4 += bf2f(h1s[s4 * 64 + f]);
        a5 += bf2f(h1s[s5 * 64 + f]);
        a6 += bf2f(h1s[s6 * 64 + f]);
        a7 += bf2f(h1s[s7 * 64 + f]);
    }
    for (; e + 3 < ee; e += 4) {
        int s0 = col[e], s1 = col[e + 1], s2 = col[e + 2], s3 = col[e + 3];
        a0 += bf2f(h1s[s0 * 64 + f]);
        a1 += bf2f(h1s[s1 * 64 + f]);
        a2 += bf2f(h1s[s2 * 64 + f]);
        a3 += bf2f(h1s[s3 * 64 + f]);
    }
    for (; e < ee; e++) a0 += bf2f(h1s[col[e] * 64 + f]);
    float dn = rsqrtf((float)(dg + 1));
    float s = ((a0 + a1) + (a2 + a3)) + ((a4 + a5) + (a6 + a7));
    out[node * 64 + f] = (s + bf2f(h1s[node * 64 + f])) * dn;
}

// ---------------- BN stats ----------------

__global__ __launch_bounds__(256) void bnstats_k(const float* __restrict__ agg1, float* __restrict__ stats, int n) {
    int f = threadIdx.x & 63, g = threadIdx.x >> 6;
    float sum = 0.f, sq = 0.f;
    for (int r = blockIdx.x * 4 + g; r < n; r += gridDim.x * 4) {
        float v = agg1[r * 64 + f];
        sum += v; sq += v * v;
    }
    __shared__ float s1[4][64], s2[4][64];
    s1[g][f] = sum; s2[g][f] = sq;
    __syncthreads();
    if (g == 0) {
        sum = s1[0][f] + s1[1][f] + s1[2][f] + s1[3][f];
        sq  = s2[0][f] + s2[1][f] + s2[2][f] + s2[3][f];
        atomicAdd(&stats[f], sum);
        atomicAdd(&stats[64 + f], sq);
    }
}

// BN folded: h = relu(agg1 * s + t);  b1 cancels in centering (shift invariance).
__global__ __launch_bounds__(64) void bnfin_k(const float* __restrict__ stats, const float* __restrict__ gamma,
                                              const float* __restrict__ beta, float* __restrict__ st, float invn) {
    int f = threadIdx.x;
    if (f < 64) {
        float mean = stats[f] * invn;
        float var = stats[64 + f] * invn - mean * mean;
        float s = gamma[f] * rsqrtf(var + BN_EPS);
        st[f] = s;
        st[64 + f] = beta[f] - mean * s;
    }
}

// ---------------- GEMM2: h2s = bf16((relu(agg1*s+t) @ W2) * dis[row])  (N x 64 @ 64 x 32) ----------------

__global__ __launch_bounds__(256) void gemm2_k(const float* __restrict__ agg1, const float* __restrict__ W2,
                                               const float* __restrict__ st, const float* __restrict__ dis,
                                               unsigned short* __restrict__ h2s, int n) {
    __shared__ __attribute__((aligned(16))) float xs[64][68];
    __shared__ __attribute__((aligned(16))) float ws2[64][32];
    __shared__ float s_s[64], s_t[64];
    if (threadIdx.x < 64) {
        s_s[threadIdx.x] = st[threadIdx.x];
        s_t[threadIdx.x] = st[64 + threadIdx.x];
    }
    for (int i = threadIdx.x; i < 512; i += 256)
        ((float4*)&ws2[0][0])[i] = ((const float4*)W2)[i];
    __syncthreads();

    int r0b = blockIdx.x * 64;
    for (int i = threadIdx.x; i < 1024; i += 256) {
        int lin = i * 4;
        int r = lin >> 6, k = lin & 63;
        int gr = r0b + r;
        float4 v = make_float4(0.f, 0.f, 0.f, 0.f);
        if (gr < n) v = ((const float4*)agg1)[(gr * 64 + k) >> 2];
        v.x = fmaxf(v.x * s_s[k + 0] + s_t[k + 0], 0.f);
        v.y = fmaxf(v.y * s_s[k + 1] + s_t[k + 1], 0.f);
        v.z = fmaxf(v.z * s_s[k + 2] + s_t[k + 2], 0.f);
        v.w = fmaxf(v.w * s_s[k + 3] + s_t[k + 3], 0.f);
        *(float4*)&xs[r][k] = v;
    }
    __syncthreads();

    int c = threadIdx.x & 31, ty = threadIdx.x >> 5;
    float acc[8] = {};
    for (int k = 0; k < 64; k++) {
        float b = ws2[k][c];
        #pragma unroll
        for (int i = 0; i < 8; i++) acc[i] += xs[ty * 8 + i][k] * b;
    }
    for (int i = 0; i < 8; i++) {
        int gr = r0b + ty * 8 + i;
        if (gr < n) h2s[gr * 32 + c] = f2bf(acc[i] * dis[gr]);
    }
}

// ---------------- Aggregation layer 2: wave per node, 2 half-waves x 32 feats, 8 gathers in flight ----------------

__global__ __launch_bounds__(256) void agg2_k(const unsigned short* __restrict__ h2s,
                                              const int2* __restrict__ rpde,
                                              const int* __restrict__ col, const float* __restrict__ b2,
                                              float* __restrict__ out, int n) {
    int node = (blockIdx.x * 256 + threadIdx.x) >> 6;
    int lane = threadIdx.x & 63;
    if (node >= n) return;
    int f = lane & 31, half = lane >> 5;
    int2 rd = rpde[node];
    int e0 = __builtin_amdgcn_readfirstlane(rd.x);
    int dg = __builtin_amdgcn_readfirstlane(rd.y);
    int e = e0 + half, ee = e0 + dg;
    float a0 = 0.f, a1 = 0.f, a2 = 0.f, a3 = 0.f;
    for (; e + 6 < ee; e += 8) {
        int s0 = col[e], s1 = col[e + 2], s2 = col[e + 4], s3 = col[e + 6];
        a0 += bf2f(h2s[s0 * 32 + f]);
        a1 += bf2f(h2s[s1 * 32 + f]);
        a2 += bf2f(h2s[s2 * 32 + f]);
        a3 += bf2f(h2s[s3 * 32 + f]);
    }
    for (; e < ee; e += 2) a0 += bf2f(h2s[col[e] * 32 + f]);
    float acc = (a0 + a1) + (a2 + a3);
    acc += __shfl_down(acc, 32, 64);
    if (half == 0) {
        float dn = rsqrtf((float)(dg + 1));
        out[node * 32 + f] = (acc + bf2f(h2s[node * 32 + f])) * dn + b2[f];
    }
}

// ---------------- launch ----------------

extern "C" void kernel_launch(void* const* d_in, const int* in_sizes, int n_in,
                              void* d_out, int out_size, void* d_ws, size_t ws_size,
                              hipStream_t stream) {
    const float* x      = (const float*)d_in[0];
    const int*   ei     = (const int*)d_in[1];
    const float* W1     = (const float*)d_in[2];
    // d_in[3] = b1 (cancels inside BN)
    const float* gamma1 = (const float*)d_in[4];
    const float* beta1  = (const float*)d_in[5];
    const float* W2     = (const float*)d_in[6];
    const float* b2     = (const float*)d_in[7];
    float* out = (float*)d_out;

    int N = in_sizes[0] / DIN;
    int E = in_sizes[1] / 2;
    const int* src = ei;
    const int* dst = ei + E;
    int nbk = (N + BK - 1) >> BKSH;         // 782
    int chunk = (E + G - 1) / G;

    size_t off = 0;  // 4B units
    auto alloc = [&](size_t elems) -> void* {
        void* p = (char*)d_ws + off * 4;
        off += (elems + 127) & ~size_t(127);
        return p;
    };
    int*            hist_g = (int*)alloc((size_t)G * NBK_MAX);
    int*            rowoff = (int*)alloc((size_t)NBK_MAX * G);
    int*            tot    = (int*)alloc(NBK_MAX);
    int*            base   = (int*)alloc(NBK_MAX + 1);
    unsigned*       recs   = (unsigned*)alloc((size_t)E);
    int*            col    = (int*)alloc((size_t)E);
    float*          dis    = (float*)alloc(N);
    int2*           rpde   = (int2*)alloc((size_t)N * 2);
    float*          stats  = (float*)alloc(128);
    float*          st     = (float*)alloc(128);
    unsigned short* h1s    = (unsigned short*)alloc((size_t)N * DH / 2);   // bf16
    float*          agg1   = (float*)alloc((size_t)N * DH);
    unsigned short* h2s    = h1s;  // h1s dead after agg1_k

    hipMemsetAsync(stats, 0, 128 * sizeof(float), stream);

    hist_k<<<G, 256, 0, stream>>>(dst, hist_g, E, nbk, chunk);
    scan_k<<<nbk, 256, 0, stream>>>(hist_g, rowoff, tot, nbk);
    base_k<<<1, 1024, 0, stream>>>(tot, base, nbk, E);
    scatter_k<<<G, 256, 0, stream>>>(src, dst, base, rowoff, recs, E, nbk, chunk);
    csr_k<<<nbk, 256, 0, stream>>>(recs, base, dis, rpde, col, N);

    gemm1_k<<<(N + 63) / 64, 256, 0, stream>>>(x, W1, dis, h1s, N);
    agg1_k<<<(N + 3) / 4, 256, 0, stream>>>(h1s, rpde, col, agg1, N);

    bnstats_k<<<400, 256, 0, stream>>>(agg1, stats, N);
    bnfin_k<<<1, 64, 0, stream>>>(stats, gamma1, beta1, st, 1.0f / (float)N);

    gemm2_k<<<(N + 63) / 64, 256, 0, stream>>>(agg1, W2, st, dis, h2s, N);
    agg2_k<<<(N + 3) / 4, 256, 0, stream>>>(h2s, rpde, col, b2, out, N);
}

// Round 8
// 295.700 us; speedup vs baseline: 1.4383x; 1.0693x over previous
//
#include <hip/hip_runtime.h>

#define DIN 128
#define DH 64
#define DOUT 32
#define BN_EPS 1e-5f

#define BK 128          // nodes per bucket
#define BKSH 7          // log2(BK)
#define NBK_MAX 784     // ceil(100000/128)=782, padded
#define G 512           // counting-sort partition blocks (fixed; scan_k assumes 512)

typedef __attribute__((ext_vector_type(8))) short short8;
typedef __attribute__((ext_vector_type(4))) float floatx4;

// bf16 helpers (RNE store, exact load)
__device__ __forceinline__ unsigned short f2bf(float f) {
    union { float f; unsigned u; } v; v.f = f;
    unsigned r = (v.u + 0x7FFFu + ((v.u >> 16) & 1u)) >> 16;
    return (unsigned short)r;
}
__device__ __forceinline__ float bf2f(unsigned short h) {
    union { unsigned u; float f; } v; v.u = ((unsigned)h) << 16;
    return v.f;
}

// ---------------- weight prep: W1^T, W2^T in bf16 (once per call) ----------------

__global__ __launch_bounds__(256) void wprep_k(const float* __restrict__ W1, const float* __restrict__ W2,
                                               unsigned short* __restrict__ w1t, unsigned short* __restrict__ w2t) {
    int i = blockIdx.x * 256 + threadIdx.x;
    if (i < 8192) {                       // W1 [128 k][64 n] -> w1t [64 n][128 k]
        int k = i >> 6, nn = i & 63;
        w1t[nn * 128 + k] = f2bf(W1[i]);
    } else if (i < 8192 + 2048) {         // W2 [64 k][32 n] -> w2t [32 n][64 k]
        int j = i - 8192;
        int k = j >> 5, nn = j & 31;
        w2t[nn * 64 + k] = f2bf(W2[j]);
    }
}

// ---------------- counting sort pass 1: per-block bucket histogram ----------------

__global__ __launch_bounds__(256) void hist_k(const int* __restrict__ dst, int* __restrict__ hist_g,
                                              int E, int nbk, int chunk) {
    __shared__ int hist[NBK_MAX];
    int g = blockIdx.x, tid = threadIdx.x;
    for (int b = tid; b < nbk; b += 256) hist[b] = 0;
    __syncthreads();
    int i0 = g * chunk, iend = min(i0 + chunk, E);
    for (int i = i0 + tid; i < iend; i += 256)
        atomicAdd(&hist[dst[i] >> BKSH], 1);
    __syncthreads();
    for (int b = tid; b < nbk; b += 256)
        hist_g[(size_t)g * nbk + b] = hist[b];   // coalesced row write
}

// ---------------- pass 2a: per-bucket exclusive scan over the G block-counts ----------------

__global__ __launch_bounds__(256) void scan_k(const int* __restrict__ hist_g, int* __restrict__ rowoff,
                                              int* __restrict__ tot, int nbk) {
    __shared__ int sa[G], sb[G];
    int b = blockIdx.x, tid = threadIdx.x;
    int v0 = hist_g[(size_t)tid * nbk + b];
    int v1 = hist_g[(size_t)(tid + 256) * nbk + b];
    sa[tid] = v0; sa[tid + 256] = v1;
    __syncthreads();
    int* pin = sa; int* pout = sb;
    for (int off = 1; off < G; off <<= 1) {
        int a0 = pin[tid] + ((tid >= off) ? pin[tid - off] : 0);
        int a1 = pin[tid + 256] + ((tid + 256 >= off) ? pin[tid + 256 - off] : 0);
        pout[tid] = a0; pout[tid + 256] = a1;
        __syncthreads();
        int* t = pin; pin = pout; pout = t;
    }
    rowoff[(size_t)b * G + tid] = pin[tid] - v0;               // exclusive, coalesced write
    rowoff[(size_t)b * G + tid + 256] = pin[tid + 256] - v1;
    if (tid == 0) tot[b] = pin[G - 1];
}

// ---------------- pass 2b: scan bucket totals -> bucket base offsets ----------------

__global__ __launch_bounds__(1024) void base_k(const int* __restrict__ tot, int* __restrict__ base,
                                               int nbk, int E) {
    __shared__ int sa[1024], sb[1024];
    int tid = threadIdx.x;
    int v = (tid < nbk) ? tot[tid] : 0;
    sa[tid] = v;
    __syncthreads();
    int* pin = sa; int* pout = sb;
    for (int off = 1; off < 1024; off <<= 1) {
        int a = pin[tid] + ((tid >= off) ? pin[tid - off] : 0);
        pout[tid] = a;
        __syncthreads();
        int* t = pin; pin = pout; pout = t;
    }
    if (tid < nbk) base[tid] = pin[tid] - v;
    if (tid == 0) base[nbk] = E;
}

// ---------------- pass 3: scatter records into dense bucket regions (no global atomics) ----------------

__global__ __launch_bounds__(256) void scatter_k(const int* __restrict__ src, const int* __restrict__ dst,
                                                 const int* __restrict__ base, const int* __restrict__ rowoff,
                                                 unsigned* __restrict__ recs, int E, int nbk, int chunk) {
    __shared__ int cur[NBK_MAX];
    int g = blockIdx.x, tid = threadIdx.x;
    for (int b = tid; b < nbk; b += 256)
        cur[b] = base[b] + rowoff[(size_t)b * G + g];
    __syncthreads();
    int i0 = g * chunk, iend = min(i0 + chunk, E);
    for (int i = i0 + tid; i < iend; i += 256) {
        int s = src[i], d = dst[i];
        int b = d >> BKSH;
        int slot = atomicAdd(&cur[b], 1);   // LDS atomic
        recs[slot] = ((unsigned)s << BKSH) | (unsigned)(d & (BK - 1));
    }
}

// ---------------- pass 4: within-bucket node sort -> CSR (col grouped by dst) ----------------

__global__ __launch_bounds__(256) void csr_k(const unsigned* __restrict__ recs, const int* __restrict__ base,
                                             float* __restrict__ dis, int2* __restrict__ rpde,
                                             int* __restrict__ col, int n) {
    __shared__ int deg[BK], bas[BK], cur[BK], sc[BK];
    int b = blockIdx.x, tid = threadIdx.x;
    if (tid < BK) { deg[tid] = 0; cur[tid] = 0; }
    __syncthreads();
    int lo = base[b], hi = base[b + 1];
    for (int e = lo + tid; e < hi; e += 256)
        atomicAdd(&deg[recs[e] & (BK - 1)], 1);
    __syncthreads();
    if (tid < BK) sc[tid] = deg[tid];
    __syncthreads();
    for (int off = 1; off < BK; off <<= 1) {
        int t = (tid >= off && tid < BK) ? sc[tid - off] : 0;
        __syncthreads();
        if (tid < BK) sc[tid] += t;
        __syncthreads();
    }
    if (tid < BK) {
        bas[tid] = sc[tid] - deg[tid];
        int g = b * BK + tid;
        if (g < n) {
            dis[g] = rsqrtf((float)(deg[tid] + 1));   // +1 self-loop
            rpde[g] = make_int2(lo + bas[tid], deg[tid]);
        }
    }
    __syncthreads();
    for (int e = lo + tid; e < hi; e += 256) {
        unsigned r = recs[e];
        int dl = r & (BK - 1);
        int k = atomicAdd(&cur[dl], 1);
        col[lo + bas[dl] + k] = (int)(r >> BKSH);
    }
}

// ---------------- GEMM1 (MFMA bf16): h1s = bf16((x @ W1) * dis[row]) ----------------
// block: 64 rows x 64 cols; 4 waves x (16 rows); K = 128 in 4 steps of 32.

__global__ __launch_bounds__(256) void gemm1_k(const float* __restrict__ x,
                                               const unsigned short* __restrict__ w1t,
                                               const float* __restrict__ dis,
                                               unsigned short* __restrict__ h1s, int n) {
    __shared__ unsigned short xb[64][136];   // +8 pad: rows 272B apart -> 2-way bank alias (free)
    __shared__ unsigned short wt[64][136];
    int tid = threadIdx.x;
    int r0b = blockIdx.x * 64;

    // stage W1^T: 64 n-rows x 128 k bf16, 16B chunks
    for (int c = tid; c < 1024; c += 256) {
        int nn = c >> 4, kc = (c & 15) * 8;
        *(short8*)&wt[nn][kc] = *(const short8*)&w1t[nn * 128 + kc];
    }
    // stage x tile fp32 -> bf16
    for (int c = tid; c < 2048; c += 256) {
        int r = c >> 5, k4 = (c & 31) * 4;
        int gr = r0b + r;
        float4 v = make_float4(0.f, 0.f, 0.f, 0.f);
        if (gr < n) v = ((const float4*)x)[(gr << 5) + (k4 >> 2)];
        ushort4 o;
        o.x = f2bf(v.x); o.y = f2bf(v.y); o.z = f2bf(v.z); o.w = f2bf(v.w);
        *(ushort4*)&xb[r][k4] = o;
    }
    __syncthreads();

    int w = tid >> 6, lane = tid & 63;
    int rr = lane & 15, q = lane >> 4;
    floatx4 acc0 = {0.f, 0.f, 0.f, 0.f}, acc1 = acc0, acc2 = acc0, acc3 = acc0;
    #pragma unroll
    for (int kt = 0; kt < 4; kt++) {
        int k0 = kt * 32 + q * 8;
        short8 a  = *(const short8*)&xb[w * 16 + rr][k0];
        short8 b0 = *(const short8*)&wt[rr][k0];
        short8 b1 = *(const short8*)&wt[16 + rr][k0];
        short8 b2 = *(const short8*)&wt[32 + rr][k0];
        short8 b3 = *(const short8*)&wt[48 + rr][k0];
        acc0 = __builtin_amdgcn_mfma_f32_16x16x32_bf16(a, b0, acc0, 0, 0, 0);
        acc1 = __builtin_amdgcn_mfma_f32_16x16x32_bf16(a, b1, acc1, 0, 0, 0);
        acc2 = __builtin_amdgcn_mfma_f32_16x16x32_bf16(a, b2, acc2, 0, 0, 0);
        acc3 = __builtin_amdgcn_mfma_f32_16x16x32_bf16(a, b3, acc3, 0, 0, 0);
    }
    // D layout: row = q*4 + t, col = rr
    #pragma unroll
    for (int t = 0; t < 4; t++) {
        int gr = r0b + w * 16 + q * 4 + t;
        if (gr < n) {
            float dd = dis[gr];
            unsigned short* o = &h1s[gr * 64];
            o[rr]      = f2bf(acc0[t] * dd);
            o[16 + rr] = f2bf(acc1[t] * dd);
            o[32 + rr] = f2bf(acc2[t] * dd);
            o[48 + rr] = f2bf(acc3[t] * dd);
        }
    }
}

// ---------------- Aggregation layer 1: wave per node, 64 lanes = 64 feats, 8 gathers in flight ----------------

__global__ __launch_bounds__(256) void agg1_k(const unsigned short* __restrict__ h1s,
                                              const int2* __restrict__ rpde,
                                              const int* __restrict__ col,
                                              unsigned short* __restrict__ out, int n) {
    int node = (blockIdx.x * 256 + threadIdx.x) >> 6;
    int f = threadIdx.x & 63;
    if (node >= n) return;
    int2 rd = rpde[node];
    int e  = __builtin_amdgcn_readfirstlane(rd.x);   // wave-uniform row start -> scalar col loads
    int dg = __builtin_amdgcn_readfirstlane(rd.y);
    int ee = e + dg;
    float a0 = 0.f, a1 = 0.f, a2 = 0.f, a3 = 0.f, a4 = 0.f, a5 = 0.f, a6 = 0.f, a7 = 0.f;
    for (; e + 7 < ee; e += 8) {
        int s0 = col[e],     s1 = col[e + 1], s2 = col[e + 2], s3 = col[e + 3];
        int s4 = col[e + 4], s5 = col[e + 5], s6 = col[e + 6], s7 = col[e + 7];
        a0 += bf2f(h1s[s0 * 64 + f]);
        a1 += bf2f(h1s[s1 * 64 + f]);
        a2 += bf2f(h1s[s2 * 64 + f]);
        a3 += bf2f(h1s[s3 * 64 + f]);
        a4 += bf2f(h1s[s4 * 64 + f]);
        a5 += bf2f(h1s[s5 * 64 + f]);
        a6 += bf2f(h1s[s6 * 64 + f]);
        a7 += bf2f(h1s[s7 * 64 + f]);
    }
    for (; e + 3 < ee; e += 4) {
        int s0 = col[e], s1 = col[e + 1], s2 = col[e + 2], s3 = col[e + 3];
        a0 += bf2f(h1s[s0 * 64 + f]);
        a1 += bf2f(h1s[s1 * 64 + f]);
        a2 += bf2f(h1s[s2 * 64 + f]);
        a3 += bf2f(h1s[s3 * 64 + f]);
    }
    for (; e < ee; e++) a0 += bf2f(h1s[col[e] * 64 + f]);
    float dn = rsqrtf((float)(dg + 1));
    float s = ((a0 + a1) + (a2 + a3)) + ((a4 + a5) + (a6 + a7));
    out[node * 64 + f] = f2bf((s + bf2f(h1s[node * 64 + f])) * dn);
}

// ---------------- BN stats (bf16 input) ----------------

__global__ __launch_bounds__(256) void bnstats_k(const unsigned short* __restrict__ agg1b,
                                                 float* __restrict__ stats, int n) {
    int f = threadIdx.x & 63, g = threadIdx.x >> 6;
    float sum = 0.f, sq = 0.f;
    for (int r = blockIdx.x * 4 + g; r < n; r += gridDim.x * 4) {
        float v = bf2f(agg1b[r * 64 + f]);
        sum += v; sq += v * v;
    }
    __shared__ float s1[4][64], s2[4][64];
    s1[g][f] = sum; s2[g][f] = sq;
    __syncthreads();
    if (g == 0) {
        sum = s1[0][f] + s1[1][f] + s1[2][f] + s1[3][f];
        sq  = s2[0][f] + s2[1][f] + s2[2][f] + s2[3][f];
        atomicAdd(&stats[f], sum);
        atomicAdd(&stats[64 + f], sq);
    }
}

// BN folded: h = relu(agg * s + t);  b1 cancels in centering (shift invariance).
__global__ __launch_bounds__(64) void bnfin_k(const float* __restrict__ stats, const float* __restrict__ gamma,
                                              const float* __restrict__ beta, float* __restrict__ st, float invn) {
    int f = threadIdx.x;
    if (f < 64) {
        float mean = stats[f] * invn;
        float var = stats[64 + f] * invn - mean * mean;
        float s = gamma[f] * rsqrtf(var + BN_EPS);
        st[f] = s;
        st[64 + f] = beta[f] - mean * s;
    }
}

// ---------------- GEMM2 (MFMA bf16): h2s = bf16((relu(agg1b*s+t) @ W2) * dis[row]) ----------------

__global__ __launch_bounds__(256) void gemm2_k(const unsigned short* __restrict__ agg1b,
                                               const unsigned short* __restrict__ w2t,
                                               const float* __restrict__ st, const float* __restrict__ dis,
                                               unsigned short* __restrict__ h2s, int n) {
    __shared__ unsigned short ab[64][72];    // +8 pad
    __shared__ unsigned short wt[32][72];
    __shared__ float s_s[64], s_t[64];
    int tid = threadIdx.x;
    int r0b = blockIdx.x * 64;
    if (tid < 64) { s_s[tid] = st[tid]; s_t[tid] = st[64 + tid]; }
    if (tid < 256) {                       // 32 n-rows x 8 chunks of 8
        int c = tid;
        int nn = c >> 3, kc = (c & 7) * 8;
        *(short8*)&wt[nn][kc] = *(const short8*)&w2t[nn * 64 + kc];
    }
    __syncthreads();
    // stage A with BN+ReLU transform, bf16
    for (int c = tid; c < 512; c += 256) {
        int r = c >> 3, k0 = (c & 7) * 8;
        int gr = r0b + r;
        unsigned short tmp[8];
        if (gr < n) {
            const unsigned short* ap = &agg1b[gr * 64 + k0];
            #pragma unroll
            for (int j = 0; j < 8; j++)
                tmp[j] = f2bf(fmaxf(bf2f(ap[j]) * s_s[k0 + j] + s_t[k0 + j], 0.f));
        } else {
            #pragma unroll
            for (int j = 0; j < 8; j++) tmp[j] = 0;
        }
        *(short8*)&ab[r][k0] = *(short8*)tmp;
    }
    __syncthreads();

    int w = tid >> 6, lane = tid & 63;
    int rr = lane & 15, q = lane >> 4;
    floatx4 acc0 = {0.f, 0.f, 0.f, 0.f}, acc1 = acc0;
    #pragma unroll
    for (int kt = 0; kt < 2; kt++) {
        int k0 = kt * 32 + q * 8;
        short8 a  = *(const short8*)&ab[w * 16 + rr][k0];
        short8 b0 = *(const short8*)&wt[rr][k0];
        short8 b1 = *(const short8*)&wt[16 + rr][k0];
        acc0 = __builtin_amdgcn_mfma_f32_16x16x32_bf16(a, b0, acc0, 0, 0, 0);
        acc1 = __builtin_amdgcn_mfma_f32_16x16x32_bf16(a, b1, acc1, 0, 0, 0);
    }
    #pragma unroll
    for (int t = 0; t < 4; t++) {
        int gr = r0b + w * 16 + q * 4 + t;
        if (gr < n) {
            float dd = dis[gr];
            h2s[gr * 32 + rr]      = f2bf(acc0[t] * dd);
            h2s[gr * 32 + 16 + rr] = f2bf(acc1[t] * dd);
        }
    }
}

// ---------------- Aggregation layer 2: wave per node, 2 half-waves x 32 feats, 16 gathers in flight ----------------

__global__ __launch_bounds__(256) void agg2_k(const unsigned short* __restrict__ h2s,
                                              const int2* __restrict__ rpde,
                                              const int* __restrict__ col, const float* __restrict__ b2,
                                              float* __restrict__ out, int n) {
    int node = (blockIdx.x * 256 + threadIdx.x) >> 6;
    int lane = threadIdx.x & 63;
    if (node >= n) return;
    int f = lane & 31, half = lane >> 5;
    int2 rd = rpde[node];
    int e0 = __builtin_amdgcn_readfirstlane(rd.x);
    int dg = __builtin_amdgcn_readfirstlane(rd.y);
    int e = e0 + half, ee = e0 + dg;
    float a0 = 0.f, a1 = 0.f, a2 = 0.f, a3 = 0.f, a4 = 0.f, a5 = 0.f, a6 = 0.f, a7 = 0.f;
    for (; e + 14 < ee; e += 16) {
        int s0 = col[e],      s1 = col[e + 2],  s2 = col[e + 4],  s3 = col[e + 6];
        int s4 = col[e + 8],  s5 = col[e + 10], s6 = col[e + 12], s7 = col[e + 14];
        a0 += bf2f(h2s[s0 * 32 + f]);
        a1 += bf2f(h2s[s1 * 32 + f]);
        a2 += bf2f(h2s[s2 * 32 + f]);
        a3 += bf2f(h2s[s3 * 32 + f]);
        a4 += bf2f(h2s[s4 * 32 + f]);
        a5 += bf2f(h2s[s5 * 32 + f]);
        a6 += bf2f(h2s[s6 * 32 + f]);
        a7 += bf2f(h2s[s7 * 32 + f]);
    }
    for (; e < ee; e += 2) a0 += bf2f(h2s[col[e] * 32 + f]);
    float acc = ((a0 + a1) + (a2 + a3)) + ((a4 + a5) + (a6 + a7));
    acc += __shfl_down(acc, 32, 64);
    if (half == 0) {
        float dn = rsqrtf((float)(dg + 1));
        out[node * 32 + f] = (acc + bf2f(h2s[node * 32 + f])) * dn + b2[f];
    }
}

// ---------------- launch ----------------

extern "C" void kernel_launch(void* const* d_in, const int* in_sizes, int n_in,
                              void* d_out, int out_size, void* d_ws, size_t ws_size,
                              hipStream_t stream) {
    const float* x      = (const float*)d_in[0];
    const int*   ei     = (const int*)d_in[1];
    const float* W1     = (const float*)d_in[2];
    // d_in[3] = b1 (cancels inside BN)
    const float* gamma1 = (const float*)d_in[4];
    const float* beta1  = (const float*)d_in[5];
    const float* W2     = (const float*)d_in[6];
    const float* b2     = (const float*)d_in[7];
    float* out = (float*)d_out;

    int N = in_sizes[0] / DIN;
    int E = in_sizes[1] / 2;
    const int* src = ei;
    const int* dst = ei + E;
    int nbk = (N + BK - 1) >> BKSH;         // 782
    int chunk = (E + G - 1) / G;

    size_t off = 0;  // 4B units
    auto alloc = [&](size_t elems) -> void* {
        void* p = (char*)d_ws + off * 4;
        off += (elems + 127) & ~size_t(127);
        return p;
    };
    int*            hist_g = (int*)alloc((size_t)G * NBK_MAX);
    int*            rowoff = (int*)alloc((size_t)NBK_MAX * G);
    int*            tot    = (int*)alloc(NBK_MAX);
    int*            base   = (int*)alloc(NBK_MAX + 1);
    unsigned*       recs   = (unsigned*)alloc((size_t)E);
    int*            col    = (int*)alloc((size_t)E);
    float*          dis    = (float*)alloc(N);
    int2*           rpde   = (int2*)alloc((size_t)N * 2);
    float*          stats  = (float*)alloc(128);
    float*          st     = (float*)alloc(128);
    unsigned short* w1t    = (unsigned short*)alloc(4096);                // 8192 bf16
    unsigned short* w2t    = (unsigned short*)alloc(1024);                // 2048 bf16
    unsigned short* h1s    = (unsigned short*)alloc((size_t)N * DH / 2);  // bf16
    unsigned short* agg1b  = (unsigned short*)alloc((size_t)N * DH / 2);  // bf16
    unsigned short* h2s    = h1s;  // h1s dead after agg1_k

    hipMemsetAsync(stats, 0, 128 * sizeof(float), stream);

    wprep_k<<<40, 256, 0, stream>>>(W1, W2, w1t, w2t);
    hist_k<<<G, 256, 0, stream>>>(dst, hist_g, E, nbk, chunk);
    scan_k<<<nbk, 256, 0, stream>>>(hist_g, rowoff, tot, nbk);
    base_k<<<1, 1024, 0, stream>>>(tot, base, nbk, E);
    scatter_k<<<G, 256, 0, stream>>>(src, dst, base, rowoff, recs, E, nbk, chunk);
    csr_k<<<nbk, 256, 0, stream>>>(recs, base, dis, rpde, col, N);

    gemm1_k<<<(N + 63) / 64, 256, 0, stream>>>(x, w1t, dis, h1s, N);
    agg1_k<<<(N + 3) / 4, 256, 0, stream>>>(h1s, rpde, col, agg1b, N);

    bnstats_k<<<400, 256, 0, stream>>>(agg1b, stats, N);
    bnfin_k<<<1, 64, 0, stream>>>(stats, gamma1, beta1, st, 1.0f / (float)N);

    gemm2_k<<<(N + 63) / 64, 256, 0, stream>>>(agg1b, w2t, st, dis, h2s, N);
    agg2_k<<<(N + 3) / 4, 256, 0, stream>>>(h2s, rpde, col, b2, out, N);
}

// Round 9
// 268.212 us; speedup vs baseline: 1.5857x; 1.1025x over previous
//
#include <hip/hip_runtime.h>

#define DIN 128
#define DH 64
#define DOUT 32
#define BN_EPS 1e-5f

#define BK 128          // nodes per bucket
#define BKSH 7          // log2(BK)
#define NBK_MAX 784     // ceil(100000/128)=782, padded
#define G 512           // counting-sort partition blocks (fixed; scan_k assumes 512)

typedef __attribute__((ext_vector_type(8))) short short8;
typedef __attribute__((ext_vector_type(4))) float floatx4;

// bf16 helpers (RNE store, exact load)
__device__ __forceinline__ unsigned short f2bf(float f) {
    union { float f; unsigned u; } v; v.f = f;
    unsigned r = (v.u + 0x7FFFu + ((v.u >> 16) & 1u)) >> 16;
    return (unsigned short)r;
}
__device__ __forceinline__ float bf2f(unsigned short h) {
    union { unsigned u; float f; } v; v.u = ((unsigned)h) << 16;
    return v.f;
}

// ---------------- weight prep: W1^T, W2^T in bf16 (once per call) ----------------

__global__ __launch_bounds__(256) void wprep_k(const float* __restrict__ W1, const float* __restrict__ W2,
                                               unsigned short* __restrict__ w1t, unsigned short* __restrict__ w2t) {
    int i = blockIdx.x * 256 + threadIdx.x;
    if (i < 8192) {                       // W1 [128 k][64 n] -> w1t [64 n][128 k]
        int k = i >> 6, nn = i & 63;
        w1t[nn * 128 + k] = f2bf(W1[i]);
    } else if (i < 8192 + 2048) {         // W2 [64 k][32 n] -> w2t [32 n][64 k]
        int j = i - 8192;
        int k = j >> 5, nn = j & 31;
        w2t[nn * 64 + k] = f2bf(W2[j]);
    }
}

// ---------------- counting sort pass 1: per-block bucket histogram ----------------

__global__ __launch_bounds__(256) void hist_k(const int* __restrict__ dst, int* __restrict__ hist_g,
                                              int E, int nbk, int chunk) {
    __shared__ int hist[NBK_MAX];
    int g = blockIdx.x, tid = threadIdx.x;
    for (int b = tid; b < nbk; b += 256) hist[b] = 0;
    __syncthreads();
    int i0 = g * chunk, iend = min(i0 + chunk, E);
    for (int i = i0 + tid; i < iend; i += 256)
        atomicAdd(&hist[dst[i] >> BKSH], 1);
    __syncthreads();
    for (int b = tid; b < nbk; b += 256)
        hist_g[(size_t)g * nbk + b] = hist[b];   // coalesced row write
}

// ---------------- pass 2a: per-bucket exclusive scan over the G block-counts ----------------

__global__ __launch_bounds__(256) void scan_k(const int* __restrict__ hist_g, int* __restrict__ rowoff,
                                              int* __restrict__ tot, int nbk) {
    __shared__ int sa[G], sb[G];
    int b = blockIdx.x, tid = threadIdx.x;
    int v0 = hist_g[(size_t)tid * nbk + b];
    int v1 = hist_g[(size_t)(tid + 256) * nbk + b];
    sa[tid] = v0; sa[tid + 256] = v1;
    __syncthreads();
    int* pin = sa; int* pout = sb;
    for (int off = 1; off < G; off <<= 1) {
        int a0 = pin[tid] + ((tid >= off) ? pin[tid - off] : 0);
        int a1 = pin[tid + 256] + ((tid + 256 >= off) ? pin[tid + 256 - off] : 0);
        pout[tid] = a0; pout[tid + 256] = a1;
        __syncthreads();
        int* t = pin; pin = pout; pout = t;
    }
    rowoff[(size_t)b * G + tid] = pin[tid] - v0;               // exclusive, coalesced write
    rowoff[(size_t)b * G + tid + 256] = pin[tid + 256] - v1;
    if (tid == 0) tot[b] = pin[G - 1];
}

// ---------------- pass 2b: scan bucket totals -> bucket base offsets ----------------

__global__ __launch_bounds__(1024) void base_k(const int* __restrict__ tot, int* __restrict__ base,
                                               int nbk, int E) {
    __shared__ int sa[1024], sb[1024];
    int tid = threadIdx.x;
    int v = (tid < nbk) ? tot[tid] : 0;
    sa[tid] = v;
    __syncthreads();
    int* pin = sa; int* pout = sb;
    for (int off = 1; off < 1024; off <<= 1) {
        int a = pin[tid] + ((tid >= off) ? pin[tid - off] : 0);
        pout[tid] = a;
        __syncthreads();
        int* t = pin; pin = pout; pout = t;
    }
    if (tid < nbk) base[tid] = pin[tid] - v;
    if (tid == 0) base[nbk] = E;
}

// ---------------- pass 3: scatter records into dense bucket regions (no global atomics) ----------------

__global__ __launch_bounds__(256) void scatter_k(const int* __restrict__ src, const int* __restrict__ dst,
                                                 const int* __restrict__ base, const int* __restrict__ rowoff,
                                                 unsigned* __restrict__ recs, int E, int nbk, int chunk) {
    __shared__ int cur[NBK_MAX];
    int g = blockIdx.x, tid = threadIdx.x;
    for (int b = tid; b < nbk; b += 256)
        cur[b] = base[b] + rowoff[(size_t)b * G + g];
    __syncthreads();
    int i0 = g * chunk, iend = min(i0 + chunk, E);
    for (int i = i0 + tid; i < iend; i += 256) {
        int s = src[i], d = dst[i];
        int b = d >> BKSH;
        int slot = atomicAdd(&cur[b], 1);   // LDS atomic
        recs[slot] = ((unsigned)s << BKSH) | (unsigned)(d & (BK - 1));
    }
}

// ---------------- pass 4: within-bucket node sort -> CSR (col grouped by dst) ----------------

__global__ __launch_bounds__(256) void csr_k(const unsigned* __restrict__ recs, const int* __restrict__ base,
                                             float* __restrict__ dis, int2* __restrict__ rpde,
                                             int* __restrict__ col, int n) {
    __shared__ int deg[BK], bas[BK], cur[BK], sc[BK];
    int b = blockIdx.x, tid = threadIdx.x;
    if (tid < BK) { deg[tid] = 0; cur[tid] = 0; }
    __syncthreads();
    int lo = base[b], hi = base[b + 1];
    for (int e = lo + tid; e < hi; e += 256)
        atomicAdd(&deg[recs[e] & (BK - 1)], 1);
    __syncthreads();
    if (tid < BK) sc[tid] = deg[tid];
    __syncthreads();
    for (int off = 1; off < BK; off <<= 1) {
        int t = (tid >= off && tid < BK) ? sc[tid - off] : 0;
        __syncthreads();
        if (tid < BK) sc[tid] += t;
        __syncthreads();
    }
    if (tid < BK) {
        bas[tid] = sc[tid] - deg[tid];
        int g = b * BK + tid;
        if (g < n) {
            dis[g] = rsqrtf((float)(deg[tid] + 1));   // +1 self-loop
            rpde[g] = make_int2(lo + bas[tid], deg[tid]);
        }
    }
    __syncthreads();
    for (int e = lo + tid; e < hi; e += 256) {
        unsigned r = recs[e];
        int dl = r & (BK - 1);
        int k = atomicAdd(&cur[dl], 1);
        col[lo + bas[dl] + k] = (int)(r >> BKSH);
    }
}

// ---------------- GEMM1 (MFMA bf16): h1s = bf16((x @ W1) * dis[row]) ----------------

__global__ __launch_bounds__(256) void gemm1_k(const float* __restrict__ x,
                                               const unsigned short* __restrict__ w1t,
                                               const float* __restrict__ dis,
                                               unsigned short* __restrict__ h1s, int n) {
    __shared__ unsigned short xb[64][136];   // +8 pad: rows 272B apart -> 2-way bank alias (free)
    __shared__ unsigned short wt[64][136];
    int tid = threadIdx.x;
    int r0b = blockIdx.x * 64;

    for (int c = tid; c < 1024; c += 256) {
        int nn = c >> 4, kc = (c & 15) * 8;
        *(short8*)&wt[nn][kc] = *(const short8*)&w1t[nn * 128 + kc];
    }
    for (int c = tid; c < 2048; c += 256) {
        int r = c >> 5, k4 = (c & 31) * 4;
        int gr = r0b + r;
        float4 v = make_float4(0.f, 0.f, 0.f, 0.f);
        if (gr < n) v = ((const float4*)x)[(gr << 5) + (k4 >> 2)];
        ushort4 o;
        o.x = f2bf(v.x); o.y = f2bf(v.y); o.z = f2bf(v.z); o.w = f2bf(v.w);
        *(ushort4*)&xb[r][k4] = o;
    }
    __syncthreads();

    int w = tid >> 6, lane = tid & 63;
    int rr = lane & 15, q = lane >> 4;
    floatx4 acc0 = {0.f, 0.f, 0.f, 0.f}, acc1 = acc0, acc2 = acc0, acc3 = acc0;
    #pragma unroll
    for (int kt = 0; kt < 4; kt++) {
        int k0 = kt * 32 + q * 8;
        short8 a  = *(const short8*)&xb[w * 16 + rr][k0];
        short8 b0 = *(const short8*)&wt[rr][k0];
        short8 b1 = *(const short8*)&wt[16 + rr][k0];
        short8 b2 = *(const short8*)&wt[32 + rr][k0];
        short8 b3 = *(const short8*)&wt[48 + rr][k0];
        acc0 = __builtin_amdgcn_mfma_f32_16x16x32_bf16(a, b0, acc0, 0, 0, 0);
        acc1 = __builtin_amdgcn_mfma_f32_16x16x32_bf16(a, b1, acc1, 0, 0, 0);
        acc2 = __builtin_amdgcn_mfma_f32_16x16x32_bf16(a, b2, acc2, 0, 0, 0);
        acc3 = __builtin_amdgcn_mfma_f32_16x16x32_bf16(a, b3, acc3, 0, 0, 0);
    }
    #pragma unroll
    for (int t = 0; t < 4; t++) {
        int gr = r0b + w * 16 + q * 4 + t;
        if (gr < n) {
            float dd = dis[gr];
            unsigned short* o = &h1s[gr * 64];
            o[rr]      = f2bf(acc0[t] * dd);
            o[16 + rr] = f2bf(acc1[t] * dd);
            o[32 + rr] = f2bf(acc2[t] * dd);
            o[48 + rr] = f2bf(acc3[t] * dd);
        }
    }
}

// ---------------- Aggregation layer 1: wave per node, predicated 8-deep gather (no serial tail) ----------------

__global__ __launch_bounds__(256) void agg1_k(const unsigned short* __restrict__ h1s,
                                              const int2* __restrict__ rpde,
                                              const int* __restrict__ col,
                                              unsigned short* __restrict__ out, int n) {
    int node = (blockIdx.x * 256 + threadIdx.x) >> 6;
    int f = threadIdx.x & 63;
    if (node >= n) return;
    int2 rd = rpde[node];
    int e  = __builtin_amdgcn_readfirstlane(rd.x);   // wave-uniform -> scalar col loads
    int dg = __builtin_amdgcn_readfirstlane(rd.y);
    float a0 = 0.f, a1 = 0.f, a2 = 0.f, a3 = 0.f, a4 = 0.f, a5 = 0.f, a6 = 0.f, a7 = 0.f;
    int full = dg & ~7;
    int b = 0;
    for (; b < full; b += 8) {
        int s0 = col[e + b],     s1 = col[e + b + 1], s2 = col[e + b + 2], s3 = col[e + b + 3];
        int s4 = col[e + b + 4], s5 = col[e + b + 5], s6 = col[e + b + 6], s7 = col[e + b + 7];
        a0 += bf2f(h1s[s0 * 64 + f]);
        a1 += bf2f(h1s[s1 * 64 + f]);
        a2 += bf2f(h1s[s2 * 64 + f]);
        a3 += bf2f(h1s[s3 * 64 + f]);
        a4 += bf2f(h1s[s4 * 64 + f]);
        a5 += bf2f(h1s[s5 * 64 + f]);
        a6 += bf2f(h1s[s6 * 64 + f]);
        a7 += bf2f(h1s[s7 * 64 + f]);
    }
    if (b < dg) {   // predicated final block: clamped indices keep 8 loads in flight
        int last = dg - 1;
        int s0 = col[e + min(b + 0, last)], s1 = col[e + min(b + 1, last)];
        int s2 = col[e + min(b + 2, last)], s3 = col[e + min(b + 3, last)];
        int s4 = col[e + min(b + 4, last)], s5 = col[e + min(b + 5, last)];
        int s6 = col[e + min(b + 6, last)], s7 = col[e + min(b + 7, last)];
        float v0 = bf2f(h1s[s0 * 64 + f]), v1 = bf2f(h1s[s1 * 64 + f]);
        float v2 = bf2f(h1s[s2 * 64 + f]), v3 = bf2f(h1s[s3 * 64 + f]);
        float v4 = bf2f(h1s[s4 * 64 + f]), v5 = bf2f(h1s[s5 * 64 + f]);
        float v6 = bf2f(h1s[s6 * 64 + f]), v7 = bf2f(h1s[s7 * 64 + f]);
        a0 += v0;                               // b < dg guaranteed
        a1 += (b + 1 < dg) ? v1 : 0.f;
        a2 += (b + 2 < dg) ? v2 : 0.f;
        a3 += (b + 3 < dg) ? v3 : 0.f;
        a4 += (b + 4 < dg) ? v4 : 0.f;
        a5 += (b + 5 < dg) ? v5 : 0.f;
        a6 += (b + 6 < dg) ? v6 : 0.f;
        a7 += (b + 7 < dg) ? v7 : 0.f;
    }
    float dn = rsqrtf((float)(dg + 1));
    float s = ((a0 + a1) + (a2 + a3)) + ((a4 + a5) + (a6 + a7));
    out[node * 64 + f] = f2bf((s + bf2f(h1s[node * 64 + f])) * dn);
}

// ---------------- BN stats (bf16 input) ----------------

__global__ __launch_bounds__(256) void bnstats_k(const unsigned short* __restrict__ agg1b,
                                                 float* __restrict__ stats, int n) {
    int f = threadIdx.x & 63, g = threadIdx.x >> 6;
    float sum = 0.f, sq = 0.f;
    for (int r = blockIdx.x * 4 + g; r < n; r += gridDim.x * 4) {
        float v = bf2f(agg1b[r * 64 + f]);
        sum += v; sq += v * v;
    }
    __shared__ float s1[4][64], s2[4][64];
    s1[g][f] = sum; s2[g][f] = sq;
    __syncthreads();
    if (g == 0) {
        sum = s1[0][f] + s1[1][f] + s1[2][f] + s1[3][f];
        sq  = s2[0][f] + s2[1][f] + s2[2][f] + s2[3][f];
        atomicAdd(&stats[f], sum);
        atomicAdd(&stats[64 + f], sq);
    }
}

// BN folded: h = relu(agg * s + t);  b1 cancels in centering (shift invariance).
__global__ __launch_bounds__(64) void bnfin_k(const float* __restrict__ stats, const float* __restrict__ gamma,
                                              const float* __restrict__ beta, float* __restrict__ st, float invn) {
    int f = threadIdx.x;
    if (f < 64) {
        float mean = stats[f] * invn;
        float var = stats[64 + f] * invn - mean * mean;
        float s = gamma[f] * rsqrtf(var + BN_EPS);
        st[f] = s;
        st[64 + f] = beta[f] - mean * s;
    }
}

// ---------------- GEMM2 (MFMA bf16): h2s = bf16((relu(agg1b*s+t) @ W2) * dis[row]) ----------------

__global__ __launch_bounds__(256) void gemm2_k(const unsigned short* __restrict__ agg1b,
                                               const unsigned short* __restrict__ w2t,
                                               const float* __restrict__ st, const float* __restrict__ dis,
                                               unsigned short* __restrict__ h2s, int n) {
    __shared__ unsigned short ab[64][72];    // +8 pad
    __shared__ unsigned short wt[32][72];
    __shared__ float s_s[64], s_t[64];
    int tid = threadIdx.x;
    int r0b = blockIdx.x * 64;
    if (tid < 64) { s_s[tid] = st[tid]; s_t[tid] = st[64 + tid]; }
    if (tid < 256) {
        int c = tid;
        int nn = c >> 3, kc = (c & 7) * 8;
        *(short8*)&wt[nn][kc] = *(const short8*)&w2t[nn * 64 + kc];
    }
    __syncthreads();
    for (int c = tid; c < 512; c += 256) {
        int r = c >> 3, k0 = (c & 7) * 8;
        int gr = r0b + r;
        unsigned short tmp[8];
        if (gr < n) {
            const unsigned short* ap = &agg1b[gr * 64 + k0];
            #pragma unroll
            for (int j = 0; j < 8; j++)
                tmp[j] = f2bf(fmaxf(bf2f(ap[j]) * s_s[k0 + j] + s_t[k0 + j], 0.f));
        } else {
            #pragma unroll
            for (int j = 0; j < 8; j++) tmp[j] = 0;
        }
        *(short8*)&ab[r][k0] = *(short8*)tmp;
    }
    __syncthreads();

    int w = tid >> 6, lane = tid & 63;
    int rr = lane & 15, q = lane >> 4;
    floatx4 acc0 = {0.f, 0.f, 0.f, 0.f}, acc1 = acc0;
    #pragma unroll
    for (int kt = 0; kt < 2; kt++) {
        int k0 = kt * 32 + q * 8;
        short8 a  = *(const short8*)&ab[w * 16 + rr][k0];
        short8 b0 = *(const short8*)&wt[rr][k0];
        short8 b1 = *(const short8*)&wt[16 + rr][k0];
        acc0 = __builtin_amdgcn_mfma_f32_16x16x32_bf16(a, b0, acc0, 0, 0, 0);
        acc1 = __builtin_amdgcn_mfma_f32_16x16x32_bf16(a, b1, acc1, 0, 0, 0);
    }
    #pragma unroll
    for (int t = 0; t < 4; t++) {
        int gr = r0b + w * 16 + q * 4 + t;
        if (gr < n) {
            float dd = dis[gr];
            h2s[gr * 32 + rr]      = f2bf(acc0[t] * dd);
            h2s[gr * 32 + 16 + rr] = f2bf(acc1[t] * dd);
        }
    }
}

// ---------------- Aggregation layer 2: node per half-wave (32 feats), predicated 8-deep gather ----------------

__global__ __launch_bounds__(256) void agg2_k(const unsigned short* __restrict__ h2s,
                                              const int2* __restrict__ rpde,
                                              const int* __restrict__ col, const float* __restrict__ b2,
                                              float* __restrict__ out, int n) {
    int wave = (blockIdx.x * 256 + threadIdx.x) >> 6;
    int lane = threadIdx.x & 63;
    int f = lane & 31, half = lane >> 5;
    int node = wave * 2 + half;
    if (node >= n) return;
    int2 rd = rpde[node];                    // uniform within half
    int e = rd.x, dg = rd.y;
    float a0 = 0.f, a1 = 0.f, a2 = 0.f, a3 = 0.f, a4 = 0.f, a5 = 0.f, a6 = 0.f, a7 = 0.f;
    int full = dg & ~7;
    int b = 0;
    for (; b < full; b += 8) {
        int s0 = col[e + b],     s1 = col[e + b + 1], s2 = col[e + b + 2], s3 = col[e + b + 3];
        int s4 = col[e + b + 4], s5 = col[e + b + 5], s6 = col[e + b + 6], s7 = col[e + b + 7];
        a0 += bf2f(h2s[s0 * 32 + f]);
        a1 += bf2f(h2s[s1 * 32 + f]);
        a2 += bf2f(h2s[s2 * 32 + f]);
        a3 += bf2f(h2s[s3 * 32 + f]);
        a4 += bf2f(h2s[s4 * 32 + f]);
        a5 += bf2f(h2s[s5 * 32 + f]);
        a6 += bf2f(h2s[s6 * 32 + f]);
        a7 += bf2f(h2s[s7 * 32 + f]);
    }
    if (b < dg) {
        int last = dg - 1;
        int s0 = col[e + min(b + 0, last)], s1 = col[e + min(b + 1, last)];
        int s2 = col[e + min(b + 2, last)], s3 = col[e + min(b + 3, last)];
        int s4 = col[e + min(b + 4, last)], s5 = col[e + min(b + 5, last)];
        int s6 = col[e + min(b + 6, last)], s7 = col[e + min(b + 7, last)];
        float v0 = bf2f(h2s[s0 * 32 + f]), v1 = bf2f(h2s[s1 * 32 + f]);
        float v2 = bf2f(h2s[s2 * 32 + f]), v3 = bf2f(h2s[s3 * 32 + f]);
        float v4 = bf2f(h2s[s4 * 32 + f]), v5 = bf2f(h2s[s5 * 32 + f]);
        float v6 = bf2f(h2s[s6 * 32 + f]), v7 = bf2f(h2s[s7 * 32 + f]);
        a0 += v0;
        a1 += (b + 1 < dg) ? v1 : 0.f;
        a2 += (b + 2 < dg) ? v2 : 0.f;
        a3 += (b + 3 < dg) ? v3 : 0.f;
        a4 += (b + 4 < dg) ? v4 : 0.f;
        a5 += (b + 5 < dg) ? v5 : 0.f;
        a6 += (b + 6 < dg) ? v6 : 0.f;
        a7 += (b + 7 < dg) ? v7 : 0.f;
    }
    float acc = ((a0 + a1) + (a2 + a3)) + ((a4 + a5) + (a6 + a7));
    float dn = rsqrtf((float)(dg + 1));
    out[node * 32 + f] = (acc + bf2f(h2s[node * 32 + f])) * dn + b2[f];
}

// ---------------- launch ----------------

extern "C" void kernel_launch(void* const* d_in, const int* in_sizes, int n_in,
                              void* d_out, int out_size, void* d_ws, size_t ws_size,
                              hipStream_t stream) {
    const float* x      = (const float*)d_in[0];
    const int*   ei     = (const int*)d_in[1];
    const float* W1     = (const float*)d_in[2];
    // d_in[3] = b1 (cancels inside BN)
    const float* gamma1 = (const float*)d_in[4];
    const float* beta1  = (const float*)d_in[5];
    const float* W2     = (const float*)d_in[6];
    const float* b2     = (const float*)d_in[7];
    float* out = (float*)d_out;

    int N = in_sizes[0] / DIN;
    int E = in_sizes[1] / 2;
    const int* src = ei;
    const int* dst = ei + E;
    int nbk = (N + BK - 1) >> BKSH;         // 782
    int chunk = (E + G - 1) / G;

    size_t off = 0;  // 4B units
    auto alloc = [&](size_t elems) -> void* {
        void* p = (char*)d_ws + off * 4;
        off += (elems + 127) & ~size_t(127);
        return p;
    };
    int*            hist_g = (int*)alloc((size_t)G * NBK_MAX);
    int*            rowoff = (int*)alloc((size_t)NBK_MAX * G);
    int*            tot    = (int*)alloc(NBK_MAX);
    int*            base   = (int*)alloc(NBK_MAX + 1);
    unsigned*       recs   = (unsigned*)alloc((size_t)E);
    int*            col    = (int*)alloc((size_t)E);
    float*          dis    = (float*)alloc(N);
    int2*           rpde   = (int2*)alloc((size_t)N * 2);
    float*          stats  = (float*)alloc(128);
    float*          st     = (float*)alloc(128);
    unsigned short* w1t    = (unsigned short*)alloc(4096);                // 8192 bf16
    unsigned short* w2t    = (unsigned short*)alloc(1024);                // 2048 bf16
    unsigned short* h1s    = (unsigned short*)alloc((size_t)N * DH / 2);  // bf16
    unsigned short* agg1b  = (unsigned short*)alloc((size_t)N * DH / 2);  // bf16
    unsigned short* h2s    = h1s;  // h1s dead after agg1_k

    hipMemsetAsync(stats, 0, 128 * sizeof(float), stream);

    wprep_k<<<40, 256, 0, stream>>>(W1, W2, w1t, w2t);
    hist_k<<<G, 256, 0, stream>>>(dst, hist_g, E, nbk, chunk);
    scan_k<<<nbk, 256, 0, stream>>>(hist_g, rowoff, tot, nbk);
    base_k<<<1, 1024, 0, stream>>>(tot, base, nbk, E);
    scatter_k<<<G, 256, 0, stream>>>(src, dst, base, rowoff, recs, E, nbk, chunk);
    csr_k<<<nbk, 256, 0, stream>>>(recs, base, dis, rpde, col, N);

    gemm1_k<<<(N + 63) / 64, 256, 0, stream>>>(x, w1t, dis, h1s, N);
    agg1_k<<<(N + 3) / 4, 256, 0, stream>>>(h1s, rpde, col, agg1b, N);

    bnstats_k<<<400, 256, 0, stream>>>(agg1b, stats, N);
    bnfin_k<<<1, 64, 0, stream>>>(stats, gamma1, beta1, st, 1.0f / (float)N);

    gemm2_k<<<(N + 63) / 64, 256, 0, stream>>>(agg1b, w2t, st, dis, h2s, N);
    agg2_k<<<(N + 7) / 8, 256, 0, stream>>>(h2s, rpde, col, b2, out, N);
}

// Round 10
// 260.845 us; speedup vs baseline: 1.6305x; 1.0282x over previous
//
#include <hip/hip_runtime.h>

#define DIN 128
#define DH 64
#define DOUT 32
#define BN_EPS 1e-5f

#define BK 128          // nodes per bucket
#define BKSH 7          // log2(BK)
#define NBK_MAX 784     // ceil(100000/128)=782, padded
#define G 512           // counting-sort partition blocks (fixed; scan_k assumes 512)

typedef __attribute__((ext_vector_type(8))) short short8;
typedef __attribute__((ext_vector_type(4))) float floatx4;

// bf16 helpers (RNE store, exact load)
__device__ __forceinline__ unsigned short f2bf(float f) {
    union { float f; unsigned u; } v; v.f = f;
    unsigned r = (v.u + 0x7FFFu + ((v.u >> 16) & 1u)) >> 16;
    return (unsigned short)r;
}
__device__ __forceinline__ float bf2f(unsigned short h) {
    union { unsigned u; float f; } v; v.u = ((unsigned)h) << 16;
    return v.f;
}
__device__ __forceinline__ float lo_f(unsigned u) {   // bf16 in low ushort -> f32
    union { unsigned u; float f; } v; v.u = u << 16;
    return v.f;
}
__device__ __forceinline__ float hi_f(unsigned u) {   // bf16 in high ushort -> f32
    union { unsigned u; float f; } v; v.u = u & 0xFFFF0000u;
    return v.f;
}
__device__ __forceinline__ unsigned pack2bf(float lo, float hi) {
    return (unsigned)f2bf(lo) | ((unsigned)f2bf(hi) << 16);
}

// ---------------- weight prep: W1^T, W2^T in bf16 (once per call) ----------------

__global__ __launch_bounds__(256) void wprep_k(const float* __restrict__ W1, const float* __restrict__ W2,
                                               unsigned short* __restrict__ w1t, unsigned short* __restrict__ w2t) {
    int i = blockIdx.x * 256 + threadIdx.x;
    if (i < 8192) {                       // W1 [128 k][64 n] -> w1t [64 n][128 k]
        int k = i >> 6, nn = i & 63;
        w1t[nn * 128 + k] = f2bf(W1[i]);
    } else if (i < 8192 + 2048) {         // W2 [64 k][32 n] -> w2t [32 n][64 k]
        int j = i - 8192;
        int k = j >> 5, nn = j & 31;
        w2t[nn * 64 + k] = f2bf(W2[j]);
    }
}

// ---------------- counting sort pass 1: per-block bucket histogram ----------------

__global__ __launch_bounds__(256) void hist_k(const int* __restrict__ dst, int* __restrict__ hist_g,
                                              int E, int nbk, int chunk) {
    __shared__ int hist[NBK_MAX];
    int g = blockIdx.x, tid = threadIdx.x;
    for (int b = tid; b < nbk; b += 256) hist[b] = 0;
    __syncthreads();
    int i0 = g * chunk, iend = min(i0 + chunk, E);
    for (int i = i0 + tid; i < iend; i += 256)
        atomicAdd(&hist[dst[i] >> BKSH], 1);
    __syncthreads();
    for (int b = tid; b < nbk; b += 256)
        hist_g[(size_t)g * nbk + b] = hist[b];   // coalesced row write
}

// ---------------- pass 2a: per-bucket exclusive scan over the G block-counts ----------------

__global__ __launch_bounds__(256) void scan_k(const int* __restrict__ hist_g, int* __restrict__ rowoff,
                                              int* __restrict__ tot, int nbk) {
    __shared__ int sa[G], sb[G];
    int b = blockIdx.x, tid = threadIdx.x;
    int v0 = hist_g[(size_t)tid * nbk + b];
    int v1 = hist_g[(size_t)(tid + 256) * nbk + b];
    sa[tid] = v0; sa[tid + 256] = v1;
    __syncthreads();
    int* pin = sa; int* pout = sb;
    for (int off = 1; off < G; off <<= 1) {
        int a0 = pin[tid] + ((tid >= off) ? pin[tid - off] : 0);
        int a1 = pin[tid + 256] + ((tid + 256 >= off) ? pin[tid + 256 - off] : 0);
        pout[tid] = a0; pout[tid + 256] = a1;
        __syncthreads();
        int* t = pin; pin = pout; pout = t;
    }
    rowoff[(size_t)b * G + tid] = pin[tid] - v0;               // exclusive, coalesced write
    rowoff[(size_t)b * G + tid + 256] = pin[tid + 256] - v1;
    if (tid == 0) tot[b] = pin[G - 1];
}

// ---------------- pass 2b: scan bucket totals -> bucket base offsets ----------------

__global__ __launch_bounds__(1024) void base_k(const int* __restrict__ tot, int* __restrict__ base,
                                               int nbk, int E) {
    __shared__ int sa[1024], sb[1024];
    int tid = threadIdx.x;
    int v = (tid < nbk) ? tot[tid] : 0;
    sa[tid] = v;
    __syncthreads();
    int* pin = sa; int* pout = sb;
    for (int off = 1; off < 1024; off <<= 1) {
        int a = pin[tid] + ((tid >= off) ? pin[tid - off] : 0);
        pout[tid] = a;
        __syncthreads();
        int* t = pin; pin = pout; pout = t;
    }
    if (tid < nbk) base[tid] = pin[tid] - v;
    if (tid == 0) base[nbk] = E;
}

// ---------------- pass 3: scatter records into dense bucket regions (no global atomics) ----------------

__global__ __launch_bounds__(256) void scatter_k(const int* __restrict__ src, const int* __restrict__ dst,
                                                 const int* __restrict__ base, const int* __restrict__ rowoff,
                                                 unsigned* __restrict__ recs, int E, int nbk, int chunk) {
    __shared__ int cur[NBK_MAX];
    int g = blockIdx.x, tid = threadIdx.x;
    for (int b = tid; b < nbk; b += 256)
        cur[b] = base[b] + rowoff[(size_t)b * G + g];
    __syncthreads();
    int i0 = g * chunk, iend = min(i0 + chunk, E);
    for (int i = i0 + tid; i < iend; i += 256) {
        int s = src[i], d = dst[i];
        int b = d >> BKSH;
        int slot = atomicAdd(&cur[b], 1);   // LDS atomic
        recs[slot] = ((unsigned)s << BKSH) | (unsigned)(d & (BK - 1));
    }
}

// ---------------- pass 4: within-bucket node sort -> CSR (col grouped by dst) ----------------

__global__ __launch_bounds__(256) void csr_k(const unsigned* __restrict__ recs, const int* __restrict__ base,
                                             float* __restrict__ dis, int2* __restrict__ rpde,
                                             int* __restrict__ col, int n) {
    __shared__ int deg[BK], bas[BK], cur[BK], sc[BK];
    int b = blockIdx.x, tid = threadIdx.x;
    if (tid < BK) { deg[tid] = 0; cur[tid] = 0; }
    __syncthreads();
    int lo = base[b], hi = base[b + 1];
    for (int e = lo + tid; e < hi; e += 256)
        atomicAdd(&deg[recs[e] & (BK - 1)], 1);
    __syncthreads();
    if (tid < BK) sc[tid] = deg[tid];
    __syncthreads();
    for (int off = 1; off < BK; off <<= 1) {
        int t = (tid >= off && tid < BK) ? sc[tid - off] : 0;
        __syncthreads();
        if (tid < BK) sc[tid] += t;
        __syncthreads();
    }
    if (tid < BK) {
        bas[tid] = sc[tid] - deg[tid];
        int g = b * BK + tid;
        if (g < n) {
            dis[g] = rsqrtf((float)(deg[tid] + 1));   // +1 self-loop
            rpde[g] = make_int2(lo + bas[tid], deg[tid]);
        }
    }
    __syncthreads();
    for (int e = lo + tid; e < hi; e += 256) {
        unsigned r = recs[e];
        int dl = r & (BK - 1);
        int k = atomicAdd(&cur[dl], 1);
        col[lo + bas[dl] + k] = (int)(r >> BKSH);
    }
}

// ---------------- GEMM1 (MFMA bf16): h1s = bf16((x @ W1) * dis[row]) ----------------

__global__ __launch_bounds__(256) void gemm1_k(const float* __restrict__ x,
                                               const unsigned short* __restrict__ w1t,
                                               const float* __restrict__ dis,
                                               unsigned short* __restrict__ h1s, int n) {
    __shared__ unsigned short xb[64][136];   // +8 pad: rows 272B apart -> 2-way bank alias (free)
    __shared__ unsigned short wt[64][136];
    int tid = threadIdx.x;
    int r0b = blockIdx.x * 64;

    for (int c = tid; c < 1024; c += 256) {
        int nn = c >> 4, kc = (c & 15) * 8;
        *(short8*)&wt[nn][kc] = *(const short8*)&w1t[nn * 128 + kc];
    }
    for (int c = tid; c < 2048; c += 256) {
        int r = c >> 5, k4 = (c & 31) * 4;
        int gr = r0b + r;
        float4 v = make_float4(0.f, 0.f, 0.f, 0.f);
        if (gr < n) v = ((const float4*)x)[(gr << 5) + (k4 >> 2)];
        ushort4 o;
        o.x = f2bf(v.x); o.y = f2bf(v.y); o.z = f2bf(v.z); o.w = f2bf(v.w);
        *(ushort4*)&xb[r][k4] = o;
    }
    __syncthreads();

    int w = tid >> 6, lane = tid & 63;
    int rr = lane & 15, q = lane >> 4;
    floatx4 acc0 = {0.f, 0.f, 0.f, 0.f}, acc1 = acc0, acc2 = acc0, acc3 = acc0;
    #pragma unroll
    for (int kt = 0; kt < 4; kt++) {
        int k0 = kt * 32 + q * 8;
        short8 a  = *(const short8*)&xb[w * 16 + rr][k0];
        short8 b0 = *(const short8*)&wt[rr][k0];
        short8 b1 = *(const short8*)&wt[16 + rr][k0];
        short8 b2 = *(const short8*)&wt[32 + rr][k0];
        short8 b3 = *(const short8*)&wt[48 + rr][k0];
        acc0 = __builtin_amdgcn_mfma_f32_16x16x32_bf16(a, b0, acc0, 0, 0, 0);
        acc1 = __builtin_amdgcn_mfma_f32_16x16x32_bf16(a, b1, acc1, 0, 0, 0);
        acc2 = __builtin_amdgcn_mfma_f32_16x16x32_bf16(a, b2, acc2, 0, 0, 0);
        acc3 = __builtin_amdgcn_mfma_f32_16x16x32_bf16(a, b3, acc3, 0, 0, 0);
    }
    #pragma unroll
    for (int t = 0; t < 4; t++) {
        int gr = r0b + w * 16 + q * 4 + t;
        if (gr < n) {
            float dd = dis[gr];
            unsigned short* o = &h1s[gr * 64];
            o[rr]      = f2bf(acc0[t] * dd);
            o[16 + rr] = f2bf(acc1[t] * dd);
            o[32 + rr] = f2bf(acc2[t] * dd);
            o[48 + rr] = f2bf(acc3[t] * dd);
        }
    }
}

// ---------------- Aggregation layer 1: wave per node, uint-packed (2 feats/lane, 2 edges/instr) ----------------
// lane = eslot*32 + f2; slot i covers edges b+2i+eslot -> 16 edges per unrolled block.

__global__ __launch_bounds__(256) void agg1_k(const unsigned* __restrict__ h1p,
                                              const int2* __restrict__ rpde,
                                              const int* __restrict__ col,
                                              unsigned* __restrict__ outp, int n) {
    int node = (blockIdx.x * 256 + threadIdx.x) >> 6;
    int lane = threadIdx.x & 63;
    if (node >= n) return;
    int f2 = lane & 31, eslot = lane >> 5;
    int2 rd = rpde[node];
    int e  = __builtin_amdgcn_readfirstlane(rd.x);
    int dg = __builtin_amdgcn_readfirstlane(rd.y);

    float lo0 = 0.f, lo1 = 0.f, lo2 = 0.f, lo3 = 0.f, lo4 = 0.f, lo5 = 0.f, lo6 = 0.f, lo7 = 0.f;
    float hi0 = 0.f, hi1 = 0.f, hi2 = 0.f, hi3 = 0.f, hi4 = 0.f, hi5 = 0.f, hi6 = 0.f, hi7 = 0.f;
    int b = 0;
    for (; b + 16 <= dg; b += 16) {
        int s0 = col[e + b + 0 + eslot],  s1 = col[e + b + 2 + eslot];
        int s2 = col[e + b + 4 + eslot],  s3 = col[e + b + 6 + eslot];
        int s4 = col[e + b + 8 + eslot],  s5 = col[e + b + 10 + eslot];
        int s6 = col[e + b + 12 + eslot], s7 = col[e + b + 14 + eslot];
        unsigned u0 = h1p[s0 * 32 + f2], u1 = h1p[s1 * 32 + f2];
        unsigned u2 = h1p[s2 * 32 + f2], u3 = h1p[s3 * 32 + f2];
        unsigned u4 = h1p[s4 * 32 + f2], u5 = h1p[s5 * 32 + f2];
        unsigned u6 = h1p[s6 * 32 + f2], u7 = h1p[s7 * 32 + f2];
        lo0 += lo_f(u0); hi0 += hi_f(u0);
        lo1 += lo_f(u1); hi1 += hi_f(u1);
        lo2 += lo_f(u2); hi2 += hi_f(u2);
        lo3 += lo_f(u3); hi3 += hi_f(u3);
        lo4 += lo_f(u4); hi4 += hi_f(u4);
        lo5 += lo_f(u5); hi5 += hi_f(u5);
        lo6 += lo_f(u6); hi6 += hi_f(u6);
        lo7 += lo_f(u7); hi7 += hi_f(u7);
    }
    if (b < dg) {
        int last = dg - 1;
        int i0 = b + 0 + eslot,  i1 = b + 2 + eslot,  i2 = b + 4 + eslot,  i3 = b + 6 + eslot;
        int i4 = b + 8 + eslot,  i5 = b + 10 + eslot, i6 = b + 12 + eslot, i7 = b + 14 + eslot;
        int s0 = col[e + min(i0, last)], s1 = col[e + min(i1, last)];
        int s2 = col[e + min(i2, last)], s3 = col[e + min(i3, last)];
        int s4 = col[e + min(i4, last)], s5 = col[e + min(i5, last)];
        int s6 = col[e + min(i6, last)], s7 = col[e + min(i7, last)];
        unsigned u0 = h1p[s0 * 32 + f2], u1 = h1p[s1 * 32 + f2];
        unsigned u2 = h1p[s2 * 32 + f2], u3 = h1p[s3 * 32 + f2];
        unsigned u4 = h1p[s4 * 32 + f2], u5 = h1p[s5 * 32 + f2];
        unsigned u6 = h1p[s6 * 32 + f2], u7 = h1p[s7 * 32 + f2];
        lo0 += (i0 < dg) ? lo_f(u0) : 0.f; hi0 += (i0 < dg) ? hi_f(u0) : 0.f;
        lo1 += (i1 < dg) ? lo_f(u1) : 0.f; hi1 += (i1 < dg) ? hi_f(u1) : 0.f;
        lo2 += (i2 < dg) ? lo_f(u2) : 0.f; hi2 += (i2 < dg) ? hi_f(u2) : 0.f;
        lo3 += (i3 < dg) ? lo_f(u3) : 0.f; hi3 += (i3 < dg) ? hi_f(u3) : 0.f;
        lo4 += (i4 < dg) ? lo_f(u4) : 0.f; hi4 += (i4 < dg) ? hi_f(u4) : 0.f;
        lo5 += (i5 < dg) ? lo_f(u5) : 0.f; hi5 += (i5 < dg) ? hi_f(u5) : 0.f;
        lo6 += (i6 < dg) ? lo_f(u6) : 0.f; hi6 += (i6 < dg) ? hi_f(u6) : 0.f;
        lo7 += (i7 < dg) ? lo_f(u7) : 0.f; hi7 += (i7 < dg) ? hi_f(u7) : 0.f;
    }
    float lo = ((lo0 + lo1) + (lo2 + lo3)) + ((lo4 + lo5) + (lo6 + lo7));
    float hi = ((hi0 + hi1) + (hi2 + hi3)) + ((hi4 + hi5) + (hi6 + hi7));
    lo += __shfl_xor(lo, 32, 64);
    hi += __shfl_xor(hi, 32, 64);
    if (eslot == 0) {
        unsigned us = h1p[node * 32 + f2];
        float dn = rsqrtf((float)(dg + 1));
        outp[node * 32 + f2] = pack2bf((lo + lo_f(us)) * dn, (hi + hi_f(us)) * dn);
    }
}

// ---------------- BN stats (bf16 input) ----------------

__global__ __launch_bounds__(256) void bnstats_k(const unsigned short* __restrict__ agg1b,
                                                 float* __restrict__ stats, int n) {
    int f = threadIdx.x & 63, g = threadIdx.x >> 6;
    float sum = 0.f, sq = 0.f;
    for (int r = blockIdx.x * 4 + g; r < n; r += gridDim.x * 4) {
        float v = bf2f(agg1b[r * 64 + f]);
        sum += v; sq += v * v;
    }
    __shared__ float s1[4][64], s2[4][64];
    s1[g][f] = sum; s2[g][f] = sq;
    __syncthreads();
    if (g == 0) {
        sum = s1[0][f] + s1[1][f] + s1[2][f] + s1[3][f];
        sq  = s2[0][f] + s2[1][f] + s2[2][f] + s2[3][f];
        atomicAdd(&stats[f], sum);
        atomicAdd(&stats[64 + f], sq);
    }
}

// ---------------- GEMM2 (MFMA bf16), BN fold inlined: h2s = bf16((relu(agg1b*s+t) @ W2) * dis[row]) ----------------

__global__ __launch_bounds__(256) void gemm2_k(const unsigned short* __restrict__ agg1b,
                                               const unsigned short* __restrict__ w2t,
                                               const float* __restrict__ stats,
                                               const float* __restrict__ gamma, const float* __restrict__ beta,
                                               const float* __restrict__ dis,
                                               unsigned short* __restrict__ h2s, float invn, int n) {
    __shared__ unsigned short ab[64][72];    // +8 pad
    __shared__ unsigned short wt[32][72];
    __shared__ float s_s[64], s_t[64];
    int tid = threadIdx.x;
    int r0b = blockIdx.x * 64;
    if (tid < 64) {                          // BN fold (b1 cancels by shift invariance)
        float mean = stats[tid] * invn;
        float var = stats[64 + tid] * invn - mean * mean;
        float s = gamma[tid] * rsqrtf(var + BN_EPS);
        s_s[tid] = s;
        s_t[tid] = beta[tid] - mean * s;
    }
    if (tid < 256) {
        int c = tid;
        int nn = c >> 3, kc = (c & 7) * 8;
        *(short8*)&wt[nn][kc] = *(const short8*)&w2t[nn * 64 + kc];
    }
    __syncthreads();
    for (int c = tid; c < 512; c += 256) {
        int r = c >> 3, k0 = (c & 7) * 8;
        int gr = r0b + r;
        unsigned short tmp[8];
        if (gr < n) {
            const unsigned short* ap = &agg1b[gr * 64 + k0];
            #pragma unroll
            for (int j = 0; j < 8; j++)
                tmp[j] = f2bf(fmaxf(bf2f(ap[j]) * s_s[k0 + j] + s_t[k0 + j], 0.f));
        } else {
            #pragma unroll
            for (int j = 0; j < 8; j++) tmp[j] = 0;
        }
        *(short8*)&ab[r][k0] = *(short8*)tmp;
    }
    __syncthreads();

    int w = tid >> 6, lane = tid & 63;
    int rr = lane & 15, q = lane >> 4;
    floatx4 acc0 = {0.f, 0.f, 0.f, 0.f}, acc1 = acc0;
    #pragma unroll
    for (int kt = 0; kt < 2; kt++) {
        int k0 = kt * 32 + q * 8;
        short8 a  = *(const short8*)&ab[w * 16 + rr][k0];
        short8 b0 = *(const short8*)&wt[rr][k0];
        short8 b1 = *(const short8*)&wt[16 + rr][k0];
        acc0 = __builtin_amdgcn_mfma_f32_16x16x32_bf16(a, b0, acc0, 0, 0, 0);
        acc1 = __builtin_amdgcn_mfma_f32_16x16x32_bf16(a, b1, acc1, 0, 0, 0);
    }
    #pragma unroll
    for (int t = 0; t < 4; t++) {
        int gr = r0b + w * 16 + q * 4 + t;
        if (gr < n) {
            float dd = dis[gr];
            h2s[gr * 32 + rr]      = f2bf(acc0[t] * dd);
            h2s[gr * 32 + 16 + rr] = f2bf(acc1[t] * dd);
        }
    }
}

// ---------------- Aggregation layer 2: node per half-wave, uint-packed (2 feats/lane, 2 edges/instr) ----------------
// within half: f2 = hl & 15 (feats 2f2,2f2+1), eslot = hl >> 4; 16 edges per unrolled block.

__global__ __launch_bounds__(256) void agg2_k(const unsigned* __restrict__ h2p,
                                              const int2* __restrict__ rpde,
                                              const int* __restrict__ col, const float* __restrict__ b2,
                                              float* __restrict__ out, int n) {
    int wave = (blockIdx.x * 256 + threadIdx.x) >> 6;
    int lane = threadIdx.x & 63;
    int half = lane >> 5, hl = lane & 31;
    int node = wave * 2 + half;
    if (node >= n) return;
    int f2 = hl & 15, eslot = hl >> 4;
    int2 rd = rpde[node];                    // uniform within half
    int e = rd.x, dg = rd.y;

    float lo0 = 0.f, lo1 = 0.f, lo2 = 0.f, lo3 = 0.f, lo4 = 0.f, lo5 = 0.f, lo6 = 0.f, lo7 = 0.f;
    float hi0 = 0.f, hi1 = 0.f, hi2 = 0.f, hi3 = 0.f, hi4 = 0.f, hi5 = 0.f, hi6 = 0.f, hi7 = 0.f;
    int b = 0;
    for (; b + 16 <= dg; b += 16) {
        int s0 = col[e + b + 0 + eslot],  s1 = col[e + b + 2 + eslot];
        int s2 = col[e + b + 4 + eslot],  s3 = col[e + b + 6 + eslot];
        int s4 = col[e + b + 8 + eslot],  s5 = col[e + b + 10 + eslot];
        int s6 = col[e + b + 12 + eslot], s7 = col[e + b + 14 + eslot];
        unsigned u0 = h2p[s0 * 16 + f2], u1 = h2p[s1 * 16 + f2];
        unsigned u2 = h2p[s2 * 16 + f2], u3 = h2p[s3 * 16 + f2];
        unsigned u4 = h2p[s4 * 16 + f2], u5 = h2p[s5 * 16 + f2];
        unsigned u6 = h2p[s6 * 16 + f2], u7 = h2p[s7 * 16 + f2];
        lo0 += lo_f(u0); hi0 += hi_f(u0);
        lo1 += lo_f(u1); hi1 += hi_f(u1);
        lo2 += lo_f(u2); hi2 += hi_f(u2);
        lo3 += lo_f(u3); hi3 += hi_f(u3);
        lo4 += lo_f(u4); hi4 += hi_f(u4);
        lo5 += lo_f(u5); hi5 += hi_f(u5);
        lo6 += lo_f(u6); hi6 += hi_f(u6);
        lo7 += lo_f(u7); hi7 += hi_f(u7);
    }
    if (b < dg) {
        int last = dg - 1;
        int i0 = b + 0 + eslot,  i1 = b + 2 + eslot,  i2 = b + 4 + eslot,  i3 = b + 6 + eslot;
        int i4 = b + 8 + eslot,  i5 = b + 10 + eslot, i6 = b + 12 + eslot, i7 = b + 14 + eslot;
        int s0 = col[e + min(i0, last)], s1 = col[e + min(i1, last)];
        int s2 = col[e + min(i2, last)], s3 = col[e + min(i3, last)];
        int s4 = col[e + min(i4, last)], s5 = col[e + min(i5, last)];
        int s6 = col[e + min(i6, last)], s7 = col[e + min(i7, last)];
        unsigned u0 = h2p[s0 * 16 + f2], u1 = h2p[s1 * 16 + f2];
        unsigned u2 = h2p[s2 * 16 + f2], u3 = h2p[s3 * 16 + f2];
        unsigned u4 = h2p[s4 * 16 + f2], u5 = h2p[s5 * 16 + f2];
        unsigned u6 = h2p[s6 * 16 + f2], u7 = h2p[s7 * 16 + f2];
        lo0 += (i0 < dg) ? lo_f(u0) : 0.f; hi0 += (i0 < dg) ? hi_f(u0) : 0.f;
        lo1 += (i1 < dg) ? lo_f(u1) : 0.f; hi1 += (i1 < dg) ? hi_f(u1) : 0.f;
        lo2 += (i2 < dg) ? lo_f(u2) : 0.f; hi2 += (i2 < dg) ? hi_f(u2) : 0.f;
        lo3 += (i3 < dg) ? lo_f(u3) : 0.f; hi3 += (i3 < dg) ? hi_f(u3) : 0.f;
        lo4 += (i4 < dg) ? lo_f(u4) : 0.f; hi4 += (i4 < dg) ? hi_f(u4) : 0.f;
        lo5 += (i5 < dg) ? lo_f(u5) : 0.f; hi5 += (i5 < dg) ? hi_f(u5) : 0.f;
        lo6 += (i6 < dg) ? lo_f(u6) : 0.f; hi6 += (i6 < dg) ? hi_f(u6) : 0.f;
        lo7 += (i7 < dg) ? lo_f(u7) : 0.f; hi7 += (i7 < dg) ? hi_f(u7) : 0.f;
    }
    float lo = ((lo0 + lo1) + (lo2 + lo3)) + ((lo4 + lo5) + (lo6 + lo7));
    float hi = ((hi0 + hi1) + (hi2 + hi3)) + ((hi4 + hi5) + (hi6 + hi7));
    lo += __shfl_xor(lo, 16, 64);            // cross-eslot within the 32-lane half
    hi += __shfl_xor(hi, 16, 64);
    if (eslot == 0) {
        unsigned us = h2p[node * 16 + f2];
        float dn = rsqrtf((float)(dg + 1));
        float2 bb = ((const float2*)b2)[f2];
        float2 o;
        o.x = (lo + lo_f(us)) * dn + bb.x;
        o.y = (hi + hi_f(us)) * dn + bb.y;
        ((float2*)out)[node * 16 + f2] = o;
    }
}

// ---------------- launch ----------------

extern "C" void kernel_launch(void* const* d_in, const int* in_sizes, int n_in,
                              void* d_out, int out_size, void* d_ws, size_t ws_size,
                              hipStream_t stream) {
    const float* x      = (const float*)d_in[0];
    const int*   ei     = (const int*)d_in[1];
    const float* W1     = (const float*)d_in[2];
    // d_in[3] = b1 (cancels inside BN)
    const float* gamma1 = (const float*)d_in[4];
    const float* beta1  = (const float*)d_in[5];
    const float* W2     = (const float*)d_in[6];
    const float* b2     = (const float*)d_in[7];
    float* out = (float*)d_out;

    int N = in_sizes[0] / DIN;
    int E = in_sizes[1] / 2;
    const int* src = ei;
    const int* dst = ei + E;
    int nbk = (N + BK - 1) >> BKSH;         // 782
    int chunk = (E + G - 1) / G;

    size_t off = 0;  // 4B units
    auto alloc = [&](size_t elems) -> void* {
        void* p = (char*)d_ws + off * 4;
        off += (elems + 127) & ~size_t(127);
        return p;
    };
    int*            hist_g = (int*)alloc((size_t)G * NBK_MAX);
    int*            rowoff = (int*)alloc((size_t)NBK_MAX * G);
    int*            tot    = (int*)alloc(NBK_MAX);
    int*            base   = (int*)alloc(NBK_MAX + 1);
    unsigned*       recs   = (unsigned*)alloc((size_t)E);
    int*            col    = (int*)alloc((size_t)E);
    float*          dis    = (float*)alloc(N);
    int2*           rpde   = (int2*)alloc((size_t)N * 2);
    float*          stats  = (float*)alloc(128);
    unsigned short* w1t    = (unsigned short*)alloc(4096);                // 8192 bf16
    unsigned short* w2t    = (unsigned short*)alloc(1024);                // 2048 bf16
    unsigned short* h1s    = (unsigned short*)alloc((size_t)N * DH / 2);  // bf16
    unsigned short* agg1b  = (unsigned short*)alloc((size_t)N * DH / 2);  // bf16
    unsigned short* h2s    = h1s;  // h1s dead after agg1_k

    hipMemsetAsync(stats, 0, 128 * sizeof(float), stream);

    wprep_k<<<40, 256, 0, stream>>>(W1, W2, w1t, w2t);
    hist_k<<<G, 256, 0, stream>>>(dst, hist_g, E, nbk, chunk);
    scan_k<<<nbk, 256, 0, stream>>>(hist_g, rowoff, tot, nbk);
    base_k<<<1, 1024, 0, stream>>>(tot, base, nbk, E);
    scatter_k<<<G, 256, 0, stream>>>(src, dst, base, rowoff, recs, E, nbk, chunk);
    csr_k<<<nbk, 256, 0, stream>>>(recs, base, dis, rpde, col, N);

    gemm1_k<<<(N + 63) / 64, 256, 0, stream>>>(x, w1t, dis, h1s, N);
    agg1_k<<<(N + 3) / 4, 256, 0, stream>>>((const unsigned*)h1s, rpde, col, (unsigned*)agg1b, N);

    bnstats_k<<<400, 256, 0, stream>>>(agg1b, stats, N);

    gemm2_k<<<(N + 63) / 64, 256, 0, stream>>>(agg1b, w2t, stats, gamma1, beta1, dis, h2s,
                                               1.0f / (float)N, N);
    agg2_k<<<(N + 7) / 8, 256, 0, stream>>>((const unsigned*)h2s, rpde, col, b2, out, N);
}

// Round 11
// 260.150 us; speedup vs baseline: 1.6348x; 1.0027x over previous
//
#include <hip/hip_runtime.h>

#define DIN 128
#define DH 64
#define DOUT 32
#define BN_EPS 1e-5f

#define BK 128          // nodes per bucket
#define BKSH 7          // log2(BK)
#define NBK_MAX 784     // ceil(100000/128)=782, padded
#define G 512           // counting-sort partition blocks (fixed; scan_k assumes 512)

typedef __attribute__((ext_vector_type(8))) short short8;
typedef __attribute__((ext_vector_type(4))) float floatx4;

// bf16 helpers (RNE store, exact load)
__device__ __forceinline__ unsigned short f2bf(float f) {
    union { float f; unsigned u; } v; v.f = f;
    unsigned r = (v.u + 0x7FFFu + ((v.u >> 16) & 1u)) >> 16;
    return (unsigned short)r;
}
__device__ __forceinline__ float bf2f(unsigned short h) {
    union { unsigned u; float f; } v; v.u = ((unsigned)h) << 16;
    return v.f;
}
__device__ __forceinline__ float lo_f(unsigned u) {   // bf16 in low ushort -> f32
    union { unsigned u; float f; } v; v.u = u << 16;
    return v.f;
}
__device__ __forceinline__ float hi_f(unsigned u) {   // bf16 in high ushort -> f32
    union { unsigned u; float f; } v; v.u = u & 0xFFFF0000u;
    return v.f;
}
__device__ __forceinline__ unsigned pack2bf(float lo, float hi) {
    return (unsigned)f2bf(lo) | ((unsigned)f2bf(hi) << 16);
}

// ---------------- weight prep: W1^T, W2^T in bf16 (once per call) ----------------

__global__ __launch_bounds__(256) void wprep_k(const float* __restrict__ W1, const float* __restrict__ W2,
                                               unsigned short* __restrict__ w1t, unsigned short* __restrict__ w2t) {
    int i = blockIdx.x * 256 + threadIdx.x;
    if (i < 8192) {                       // W1 [128 k][64 n] -> w1t [64 n][128 k]
        int k = i >> 6, nn = i & 63;
        w1t[nn * 128 + k] = f2bf(W1[i]);
    } else if (i < 8192 + 2048) {         // W2 [64 k][32 n] -> w2t [32 n][64 k]
        int j = i - 8192;
        int k = j >> 5, nn = j & 31;
        w2t[nn * 64 + k] = f2bf(W2[j]);
    }
}

// ---------------- counting sort pass 1: per-block bucket histogram (g-major write) ----------------

__global__ __launch_bounds__(256) void hist_k(const int* __restrict__ dst, int* __restrict__ hist_g,
                                              int E, int nbk, int chunk) {
    __shared__ int hist[NBK_MAX];
    int g = blockIdx.x, tid = threadIdx.x;
    for (int b = tid; b < nbk; b += 256) hist[b] = 0;
    __syncthreads();
    int i0 = g * chunk, iend = min(i0 + chunk, E);
    for (int i = i0 + tid; i < iend; i += 256)
        atomicAdd(&hist[dst[i] >> BKSH], 1);
    __syncthreads();
    for (int b = tid; b < nbk; b += 256)
        hist_g[(size_t)g * nbk + b] = hist[b];   // coalesced row write
}

// ---------------- pass 2a: per-bucket exclusive scan over the G block-counts ----------------
// 16 buckets per block; thread (gl,bl) serially sums g-slice [gl*32, gl*32+32) -> LDS scan across
// the 16 segments -> coalesced g-major rowoff writes. All loads/writes are 64B-segment coalesced.

__global__ __launch_bounds__(256) void scan_k(const int* __restrict__ hist_g, int* __restrict__ rowoff,
                                              int* __restrict__ tot, int nbk) {
    __shared__ int seg[16][17];
    int tid = threadIdx.x;
    int gl = tid >> 4, bl = tid & 15;
    int b = blockIdx.x * 16 + bl;
    bool bok = b < nbk;
    int vals[32];
    int psum = 0;
    #pragma unroll
    for (int j = 0; j < 32; j++) {
        int g = gl * 32 + j;
        int v = bok ? hist_g[(size_t)g * nbk + b] : 0;   // 32 independent loads in flight
        vals[j] = v; psum += v;
    }
    seg[gl][bl] = psum;
    __syncthreads();
    #pragma unroll
    for (int off = 1; off < 16; off <<= 1) {
        int t = (gl >= off) ? seg[gl - off][bl] : 0;
        __syncthreads();
        seg[gl][bl] += t;
        __syncthreads();
    }
    int run = seg[gl][bl] - psum;                        // exclusive base of this 32-g segment
    if (gl == 15 && bok) tot[b] = seg[15][bl];
    #pragma unroll
    for (int j = 0; j < 32; j++) {
        int g = gl * 32 + j;
        if (bok) rowoff[(size_t)g * nbk + b] = run;      // g-major: scatter_k reads rows coalesced
        run += vals[j];
    }
}

// ---------------- pass 2b: scan bucket totals -> bucket base offsets ----------------

__global__ __launch_bounds__(1024) void base_k(const int* __restrict__ tot, int* __restrict__ base,
                                               int nbk, int E) {
    __shared__ int sa[1024], sb[1024];
    int tid = threadIdx.x;
    int v = (tid < nbk) ? tot[tid] : 0;
    sa[tid] = v;
    __syncthreads();
    int* pin = sa; int* pout = sb;
    for (int off = 1; off < 1024; off <<= 1) {
        int a = pin[tid] + ((tid >= off) ? pin[tid - off] : 0);
        pout[tid] = a;
        __syncthreads();
        int* t = pin; pin = pout; pout = t;
    }
    if (tid < nbk) base[tid] = pin[tid] - v;
    if (tid == 0) base[nbk] = E;
}

// ---------------- pass 3: scatter records into dense bucket regions (no global atomics) ----------------

__global__ __launch_bounds__(256) void scatter_k(const int* __restrict__ src, const int* __restrict__ dst,
                                                 const int* __restrict__ base, const int* __restrict__ rowoff,
                                                 unsigned* __restrict__ recs, int E, int nbk, int chunk) {
    __shared__ int cur[NBK_MAX];
    int g = blockIdx.x, tid = threadIdx.x;
    for (int b = tid; b < nbk; b += 256)
        cur[b] = base[b] + rowoff[(size_t)g * nbk + b];   // coalesced row read (g-major)
    __syncthreads();
    int i0 = g * chunk, iend = min(i0 + chunk, E);
    for (int i = i0 + tid; i < iend; i += 256) {
        int s = src[i], d = dst[i];
        int b = d >> BKSH;
        int slot = atomicAdd(&cur[b], 1);   // LDS atomic
        recs[slot] = ((unsigned)s << BKSH) | (unsigned)(d & (BK - 1));
    }
}

// ---------------- pass 4: within-bucket node sort -> CSR (col grouped by dst) ----------------

__global__ __launch_bounds__(256) void csr_k(const unsigned* __restrict__ recs, const int* __restrict__ base,
                                             float* __restrict__ dis, int2* __restrict__ rpde,
                                             int* __restrict__ col, int n) {
    __shared__ int deg[BK], bas[BK], cur[BK], sc[BK];
    int b = blockIdx.x, tid = threadIdx.x;
    if (tid < BK) { deg[tid] = 0; cur[tid] = 0; }
    __syncthreads();
    int lo = base[b], hi = base[b + 1];
    for (int e = lo + tid; e < hi; e += 256)
        atomicAdd(&deg[recs[e] & (BK - 1)], 1);
    __syncthreads();
    if (tid < BK) sc[tid] = deg[tid];
    __syncthreads();
    for (int off = 1; off < BK; off <<= 1) {
        int t = (tid >= off && tid < BK) ? sc[tid - off] : 0;
        __syncthreads();
        if (tid < BK) sc[tid] += t;
        __syncthreads();
    }
    if (tid < BK) {
        bas[tid] = sc[tid] - deg[tid];
        int g = b * BK + tid;
        if (g < n) {
            dis[g] = rsqrtf((float)(deg[tid] + 1));   // +1 self-loop
            rpde[g] = make_int2(lo + bas[tid], deg[tid]);
        }
    }
    __syncthreads();
    for (int e = lo + tid; e < hi; e += 256) {
        unsigned r = recs[e];
        int dl = r & (BK - 1);
        int k = atomicAdd(&cur[dl], 1);
        col[lo + bas[dl] + k] = (int)(r >> BKSH);
    }
}

// ---------------- GEMM1 (MFMA bf16): h1s = bf16((x @ W1) * dis[row]) ----------------

__global__ __launch_bounds__(256) void gemm1_k(const float* __restrict__ x,
                                               const unsigned short* __restrict__ w1t,
                                               const float* __restrict__ dis,
                                               unsigned short* __restrict__ h1s, int n) {
    __shared__ unsigned short xb[64][136];   // +8 pad: rows 272B apart -> 2-way bank alias (free)
    __shared__ unsigned short wt[64][136];
    int tid = threadIdx.x;
    int r0b = blockIdx.x * 64;

    for (int c = tid; c < 1024; c += 256) {
        int nn = c >> 4, kc = (c & 15) * 8;
        *(short8*)&wt[nn][kc] = *(const short8*)&w1t[nn * 128 + kc];
    }
    for (int c = tid; c < 2048; c += 256) {
        int r = c >> 5, k4 = (c & 31) * 4;
        int gr = r0b + r;
        float4 v = make_float4(0.f, 0.f, 0.f, 0.f);
        if (gr < n) v = ((const float4*)x)[(gr << 5) + (k4 >> 2)];
        ushort4 o;
        o.x = f2bf(v.x); o.y = f2bf(v.y); o.z = f2bf(v.z); o.w = f2bf(v.w);
        *(ushort4*)&xb[r][k4] = o;
    }
    __syncthreads();

    int w = tid >> 6, lane = tid & 63;
    int rr = lane & 15, q = lane >> 4;
    floatx4 acc0 = {0.f, 0.f, 0.f, 0.f}, acc1 = acc0, acc2 = acc0, acc3 = acc0;
    #pragma unroll
    for (int kt = 0; kt < 4; kt++) {
        int k0 = kt * 32 + q * 8;
        short8 a  = *(const short8*)&xb[w * 16 + rr][k0];
        short8 b0 = *(const short8*)&wt[rr][k0];
        short8 b1 = *(const short8*)&wt[16 + rr][k0];
        short8 b2 = *(const short8*)&wt[32 + rr][k0];
        short8 b3 = *(const short8*)&wt[48 + rr][k0];
        acc0 = __builtin_amdgcn_mfma_f32_16x16x32_bf16(a, b0, acc0, 0, 0, 0);
        acc1 = __builtin_amdgcn_mfma_f32_16x16x32_bf16(a, b1, acc1, 0, 0, 0);
        acc2 = __builtin_amdgcn_mfma_f32_16x16x32_bf16(a, b2, acc2, 0, 0, 0);
        acc3 = __builtin_amdgcn_mfma_f32_16x16x32_bf16(a, b3, acc3, 0, 0, 0);
    }
    #pragma unroll
    for (int t = 0; t < 4; t++) {
        int gr = r0b + w * 16 + q * 4 + t;
        if (gr < n) {
            float dd = dis[gr];
            unsigned short* o = &h1s[gr * 64];
            o[rr]      = f2bf(acc0[t] * dd);
            o[16 + rr] = f2bf(acc1[t] * dd);
            o[32 + rr] = f2bf(acc2[t] * dd);
            o[48 + rr] = f2bf(acc3[t] * dd);
        }
    }
}

// ---------------- Aggregation layer 1: wave per node, uint-packed (2 feats/lane, 2 edges/instr) ----------------

__global__ __launch_bounds__(256) void agg1_k(const unsigned* __restrict__ h1p,
                                              const int2* __restrict__ rpde,
                                              const int* __restrict__ col,
                                              unsigned* __restrict__ outp, int n) {
    int node = (blockIdx.x * 256 + threadIdx.x) >> 6;
    int lane = threadIdx.x & 63;
    if (node >= n) return;
    int f2 = lane & 31, eslot = lane >> 5;
    int2 rd = rpde[node];
    int e  = __builtin_amdgcn_readfirstlane(rd.x);
    int dg = __builtin_amdgcn_readfirstlane(rd.y);

    float lo0 = 0.f, lo1 = 0.f, lo2 = 0.f, lo3 = 0.f, lo4 = 0.f, lo5 = 0.f, lo6 = 0.f, lo7 = 0.f;
    float hi0 = 0.f, hi1 = 0.f, hi2 = 0.f, hi3 = 0.f, hi4 = 0.f, hi5 = 0.f, hi6 = 0.f, hi7 = 0.f;
    int b = 0;
    for (; b + 16 <= dg; b += 16) {
        int s0 = col[e + b + 0 + eslot],  s1 = col[e + b + 2 + eslot];
        int s2 = col[e + b + 4 + eslot],  s3 = col[e + b + 6 + eslot];
        int s4 = col[e + b + 8 + eslot],  s5 = col[e + b + 10 + eslot];
        int s6 = col[e + b + 12 + eslot], s7 = col[e + b + 14 + eslot];
        unsigned u0 = h1p[s0 * 32 + f2], u1 = h1p[s1 * 32 + f2];
        unsigned u2 = h1p[s2 * 32 + f2], u3 = h1p[s3 * 32 + f2];
        unsigned u4 = h1p[s4 * 32 + f2], u5 = h1p[s5 * 32 + f2];
        unsigned u6 = h1p[s6 * 32 + f2], u7 = h1p[s7 * 32 + f2];
        lo0 += lo_f(u0); hi0 += hi_f(u0);
        lo1 += lo_f(u1); hi1 += hi_f(u1);
        lo2 += lo_f(u2); hi2 += hi_f(u2);
        lo3 += lo_f(u3); hi3 += hi_f(u3);
        lo4 += lo_f(u4); hi4 += hi_f(u4);
        lo5 += lo_f(u5); hi5 += hi_f(u5);
        lo6 += lo_f(u6); hi6 += hi_f(u6);
        lo7 += lo_f(u7); hi7 += hi_f(u7);
    }
    if (b < dg) {
        int last = dg - 1;
        int i0 = b + 0 + eslot,  i1 = b + 2 + eslot,  i2 = b + 4 + eslot,  i3 = b + 6 + eslot;
        int i4 = b + 8 + eslot,  i5 = b + 10 + eslot, i6 = b + 12 + eslot, i7 = b + 14 + eslot;
        int s0 = col[e + min(i0, last)], s1 = col[e + min(i1, last)];
        int s2 = col[e + min(i2, last)], s3 = col[e + min(i3, last)];
        int s4 = col[e + min(i4, last)], s5 = col[e + min(i5, last)];
        int s6 = col[e + min(i6, last)], s7 = col[e + min(i7, last)];
        unsigned u0 = h1p[s0 * 32 + f2], u1 = h1p[s1 * 32 + f2];
        unsigned u2 = h1p[s2 * 32 + f2], u3 = h1p[s3 * 32 + f2];
        unsigned u4 = h1p[s4 * 32 + f2], u5 = h1p[s5 * 32 + f2];
        unsigned u6 = h1p[s6 * 32 + f2], u7 = h1p[s7 * 32 + f2];
        lo0 += (i0 < dg) ? lo_f(u0) : 0.f; hi0 += (i0 < dg) ? hi_f(u0) : 0.f;
        lo1 += (i1 < dg) ? lo_f(u1) : 0.f; hi1 += (i1 < dg) ? hi_f(u1) : 0.f;
        lo2 += (i2 < dg) ? lo_f(u2) : 0.f; hi2 += (i2 < dg) ? hi_f(u2) : 0.f;
        lo3 += (i3 < dg) ? lo_f(u3) : 0.f; hi3 += (i3 < dg) ? hi_f(u3) : 0.f;
        lo4 += (i4 < dg) ? lo_f(u4) : 0.f; hi4 += (i4 < dg) ? hi_f(u4) : 0.f;
        lo5 += (i5 < dg) ? lo_f(u5) : 0.f; hi5 += (i5 < dg) ? hi_f(u5) : 0.f;
        lo6 += (i6 < dg) ? lo_f(u6) : 0.f; hi6 += (i6 < dg) ? hi_f(u6) : 0.f;
        lo7 += (i7 < dg) ? lo_f(u7) : 0.f; hi7 += (i7 < dg) ? hi_f(u7) : 0.f;
    }
    float lo = ((lo0 + lo1) + (lo2 + lo3)) + ((lo4 + lo5) + (lo6 + lo7));
    float hi = ((hi0 + hi1) + (hi2 + hi3)) + ((hi4 + hi5) + (hi6 + hi7));
    lo += __shfl_xor(lo, 32, 64);
    hi += __shfl_xor(hi, 32, 64);
    if (eslot == 0) {
        unsigned us = h1p[node * 32 + f2];
        float dn = rsqrtf((float)(dg + 1));
        outp[node * 32 + f2] = pack2bf((lo + lo_f(us)) * dn, (hi + hi_f(us)) * dn);
    }
}

// ---------------- BN stats (bf16 input) ----------------

__global__ __launch_bounds__(256) void bnstats_k(const unsigned short* __restrict__ agg1b,
                                                 float* __restrict__ stats, int n) {
    int f = threadIdx.x & 63, g = threadIdx.x >> 6;
    float sum = 0.f, sq = 0.f;
    for (int r = blockIdx.x * 4 + g; r < n; r += gridDim.x * 4) {
        float v = bf2f(agg1b[r * 64 + f]);
        sum += v; sq += v * v;
    }
    __shared__ float s1[4][64], s2[4][64];
    s1[g][f] = sum; s2[g][f] = sq;
    __syncthreads();
    if (g == 0) {
        sum = s1[0][f] + s1[1][f] + s1[2][f] + s1[3][f];
        sq  = s2[0][f] + s2[1][f] + s2[2][f] + s2[3][f];
        atomicAdd(&stats[f], sum);
        atomicAdd(&stats[64 + f], sq);
    }
}

// ---------------- GEMM2 (MFMA bf16), BN fold inlined: h2s = bf16((relu(agg1b*s+t) @ W2) * dis[row]) ----------------

__global__ __launch_bounds__(256) void gemm2_k(const unsigned short* __restrict__ agg1b,
                                               const unsigned short* __restrict__ w2t,
                                               const float* __restrict__ stats,
                                               const float* __restrict__ gamma, const float* __restrict__ beta,
                                               const float* __restrict__ dis,
                                               unsigned short* __restrict__ h2s, float invn, int n) {
    __shared__ unsigned short ab[64][72];    // +8 pad
    __shared__ unsigned short wt[32][72];
    __shared__ float s_s[64], s_t[64];
    int tid = threadIdx.x;
    int r0b = blockIdx.x * 64;
    if (tid < 64) {                          // BN fold (b1 cancels by shift invariance)
        float mean = stats[tid] * invn;
        float var = stats[64 + tid] * invn - mean * mean;
        float s = gamma[tid] * rsqrtf(var + BN_EPS);
        s_s[tid] = s;
        s_t[tid] = beta[tid] - mean * s;
    }
    if (tid < 256) {
        int c = tid;
        int nn = c >> 3, kc = (c & 7) * 8;
        *(short8*)&wt[nn][kc] = *(const short8*)&w2t[nn * 64 + kc];
    }
    __syncthreads();
    for (int c = tid; c < 512; c += 256) {
        int r = c >> 3, k0 = (c & 7) * 8;
        int gr = r0b + r;
        unsigned short tmp[8];
        if (gr < n) {
            const unsigned short* ap = &agg1b[gr * 64 + k0];
            #pragma unroll
            for (int j = 0; j < 8; j++)
                tmp[j] = f2bf(fmaxf(bf2f(ap[j]) * s_s[k0 + j] + s_t[k0 + j], 0.f));
        } else {
            #pragma unroll
            for (int j = 0; j < 8; j++) tmp[j] = 0;
        }
        *(short8*)&ab[r][k0] = *(short8*)tmp;
    }
    __syncthreads();

    int w = tid >> 6, lane = tid & 63;
    int rr = lane & 15, q = lane >> 4;
    floatx4 acc0 = {0.f, 0.f, 0.f, 0.f}, acc1 = acc0;
    #pragma unroll
    for (int kt = 0; kt < 2; kt++) {
        int k0 = kt * 32 + q * 8;
        short8 a  = *(const short8*)&ab[w * 16 + rr][k0];
        short8 b0 = *(const short8*)&wt[rr][k0];
        short8 b1 = *(const short8*)&wt[16 + rr][k0];
        acc0 = __builtin_amdgcn_mfma_f32_16x16x32_bf16(a, b0, acc0, 0, 0, 0);
        acc1 = __builtin_amdgcn_mfma_f32_16x16x32_bf16(a, b1, acc1, 0, 0, 0);
    }
    #pragma unroll
    for (int t = 0; t < 4; t++) {
        int gr = r0b + w * 16 + q * 4 + t;
        if (gr < n) {
            float dd = dis[gr];
            h2s[gr * 32 + rr]      = f2bf(acc0[t] * dd);
            h2s[gr * 32 + 16 + rr] = f2bf(acc1[t] * dd);
        }
    }
}

// ---------------- Aggregation layer 2: node per half-wave, uint-packed (2 feats/lane, 2 edges/instr) ----------------

__global__ __launch_bounds__(256) void agg2_k(const unsigned* __restrict__ h2p,
                                              const int2* __restrict__ rpde,
                                              const int* __restrict__ col, const float* __restrict__ b2,
                                              float* __restrict__ out, int n) {
    int wave = (blockIdx.x * 256 + threadIdx.x) >> 6;
    int lane = threadIdx.x & 63;
    int half = lane >> 5, hl = lane & 31;
    int node = wave * 2 + half;
    if (node >= n) return;
    int f2 = hl & 15, eslot = hl >> 4;
    int2 rd = rpde[node];                    // uniform within half
    int e = rd.x, dg = rd.y;

    float lo0 = 0.f, lo1 = 0.f, lo2 = 0.f, lo3 = 0.f, lo4 = 0.f, lo5 = 0.f, lo6 = 0.f, lo7 = 0.f;
    float hi0 = 0.f, hi1 = 0.f, hi2 = 0.f, hi3 = 0.f, hi4 = 0.f, hi5 = 0.f, hi6 = 0.f, hi7 = 0.f;
    int b = 0;
    for (; b + 16 <= dg; b += 16) {
        int s0 = col[e + b + 0 + eslot],  s1 = col[e + b + 2 + eslot];
        int s2 = col[e + b + 4 + eslot],  s3 = col[e + b + 6 + eslot];
        int s4 = col[e + b + 8 + eslot],  s5 = col[e + b + 10 + eslot];
        int s6 = col[e + b + 12 + eslot], s7 = col[e + b + 14 + eslot];
        unsigned u0 = h2p[s0 * 16 + f2], u1 = h2p[s1 * 16 + f2];
        unsigned u2 = h2p[s2 * 16 + f2], u3 = h2p[s3 * 16 + f2];
        unsigned u4 = h2p[s4 * 16 + f2], u5 = h2p[s5 * 16 + f2];
        unsigned u6 = h2p[s6 * 16 + f2], u7 = h2p[s7 * 16 + f2];
        lo0 += lo_f(u0); hi0 += hi_f(u0);
        lo1 += lo_f(u1); hi1 += hi_f(u1);
        lo2 += lo_f(u2); hi2 += hi_f(u2);
        lo3 += lo_f(u3); hi3 += hi_f(u3);
        lo4 += lo_f(u4); hi4 += hi_f(u4);
        lo5 += lo_f(u5); hi5 += hi_f(u5);
        lo6 += lo_f(u6); hi6 += hi_f(u6);
        lo7 += lo_f(u7); hi7 += hi_f(u7);
    }
    if (b < dg) {
        int last = dg - 1;
        int i0 = b + 0 + eslot,  i1 = b + 2 + eslot,  i2 = b + 4 + eslot,  i3 = b + 6 + eslot;
        int i4 = b + 8 + eslot,  i5 = b + 10 + eslot, i6 = b + 12 + eslot, i7 = b + 14 + eslot;
        int s0 = col[e + min(i0, last)], s1 = col[e + min(i1, last)];
        int s2 = col[e + min(i2, last)], s3 = col[e + min(i3, last)];
        int s4 = col[e + min(i4, last)], s5 = col[e + min(i5, last)];
        int s6 = col[e + min(i6, last)], s7 = col[e + min(i7, last)];
        unsigned u0 = h2p[s0 * 16 + f2], u1 = h2p[s1 * 16 + f2];
        unsigned u2 = h2p[s2 * 16 + f2], u3 = h2p[s3 * 16 + f2];
        unsigned u4 = h2p[s4 * 16 + f2], u5 = h2p[s5 * 16 + f2];
        unsigned u6 = h2p[s6 * 16 + f2], u7 = h2p[s7 * 16 + f2];
        lo0 += (i0 < dg) ? lo_f(u0) : 0.f; hi0 += (i0 < dg) ? hi_f(u0) : 0.f;
        lo1 += (i1 < dg) ? lo_f(u1) : 0.f; hi1 += (i1 < dg) ? hi_f(u1) : 0.f;
        lo2 += (i2 < dg) ? lo_f(u2) : 0.f; hi2 += (i2 < dg) ? hi_f(u2) : 0.f;
        lo3 += (i3 < dg) ? lo_f(u3) : 0.f; hi3 += (i3 < dg) ? hi_f(u3) : 0.f;
        lo4 += (i4 < dg) ? lo_f(u4) : 0.f; hi4 += (i4 < dg) ? hi_f(u4) : 0.f;
        lo5 += (i5 < dg) ? lo_f(u5) : 0.f; hi5 += (i5 < dg) ? hi_f(u5) : 0.f;
        lo6 += (i6 < dg) ? lo_f(u6) : 0.f; hi6 += (i6 < dg) ? hi_f(u6) : 0.f;
        lo7 += (i7 < dg) ? lo_f(u7) : 0.f; hi7 += (i7 < dg) ? hi_f(u7) : 0.f;
    }
    float lo = ((lo0 + lo1) + (lo2 + lo3)) + ((lo4 + lo5) + (lo6 + lo7));
    float hi = ((hi0 + hi1) + (hi2 + hi3)) + ((hi4 + hi5) + (hi6 + hi7));
    lo += __shfl_xor(lo, 16, 64);            // cross-eslot within the 32-lane half
    hi += __shfl_xor(hi, 16, 64);
    if (eslot == 0) {
        unsigned us = h2p[node * 16 + f2];
        float dn = rsqrtf((float)(dg + 1));
        float2 bb = ((const float2*)b2)[f2];
        float2 o;
        o.x = (lo + lo_f(us)) * dn + bb.x;
        o.y = (hi + hi_f(us)) * dn + bb.y;
        ((float2*)out)[node * 16 + f2] = o;
    }
}

// ---------------- launch ----------------

extern "C" void kernel_launch(void* const* d_in, const int* in_sizes, int n_in,
                              void* d_out, int out_size, void* d_ws, size_t ws_size,
                              hipStream_t stream) {
    const float* x      = (const float*)d_in[0];
    const int*   ei     = (const int*)d_in[1];
    const float* W1     = (const float*)d_in[2];
    // d_in[3] = b1 (cancels inside BN)
    const float* gamma1 = (const float*)d_in[4];
    const float* beta1  = (const float*)d_in[5];
    const float* W2     = (const float*)d_in[6];
    const float* b2     = (const float*)d_in[7];
    float* out = (float*)d_out;

    int N = in_sizes[0] / DIN;
    int E = in_sizes[1] / 2;
    const int* src = ei;
    const int* dst = ei + E;
    int nbk = (N + BK - 1) >> BKSH;         // 782
    int chunk = (E + G - 1) / G;

    size_t off = 0;  // 4B units
    auto alloc = [&](size_t elems) -> void* {
        void* p = (char*)d_ws + off * 4;
        off += (elems + 127) & ~size_t(127);
        return p;
    };
    int*            hist_g = (int*)alloc((size_t)G * NBK_MAX);
    int*            rowoff = (int*)alloc((size_t)G * NBK_MAX);   // g-major [G][nbk]
    int*            tot    = (int*)alloc(NBK_MAX);
    int*            base   = (int*)alloc(NBK_MAX + 1);
    unsigned*       recs   = (unsigned*)alloc((size_t)E);
    int*            col    = (int*)alloc((size_t)E);
    float*          dis    = (float*)alloc(N);
    int2*           rpde   = (int2*)alloc((size_t)N * 2);
    float*          stats  = (float*)alloc(128);
    unsigned short* w1t    = (unsigned short*)alloc(4096);                // 8192 bf16
    unsigned short* w2t    = (unsigned short*)alloc(1024);                // 2048 bf16
    unsigned short* h1s    = (unsigned short*)alloc((size_t)N * DH / 2);  // bf16
    unsigned short* agg1b  = (unsigned short*)alloc((size_t)N * DH / 2);  // bf16
    unsigned short* h2s    = h1s;  // h1s dead after agg1_k

    hipMemsetAsync(stats, 0, 128 * sizeof(float), stream);

    wprep_k<<<40, 256, 0, stream>>>(W1, W2, w1t, w2t);
    hist_k<<<G, 256, 0, stream>>>(dst, hist_g, E, nbk, chunk);
    scan_k<<<(nbk + 15) / 16, 256, 0, stream>>>(hist_g, rowoff, tot, nbk);
    base_k<<<1, 1024, 0, stream>>>(tot, base, nbk, E);
    scatter_k<<<G, 256, 0, stream>>>(src, dst, base, rowoff, recs, E, nbk, chunk);
    csr_k<<<nbk, 256, 0, stream>>>(recs, base, dis, rpde, col, N);

    gemm1_k<<<(N + 63) / 64, 256, 0, stream>>>(x, w1t, dis, h1s, N);
    agg1_k<<<(N + 3) / 4, 256, 0, stream>>>((const unsigned*)h1s, rpde, col, (unsigned*)agg1b, N);

    bnstats_k<<<400, 256, 0, stream>>>(agg1b, stats, N);

    gemm2_k<<<(N + 63) / 64, 256, 0, stream>>>(agg1b, w2t, stats, gamma1, beta1, dis, h2s,
                                               1.0f / (float)N, N);
    agg2_k<<<(N + 7) / 8, 256, 0, stream>>>((const unsigned*)h2s, rpde, col, b2, out, N);
}